// Round 1
// baseline (458.444 us; speedup 1.0000x reference)
//
#include <hip/hip_runtime.h>
#include <hip/hip_bf16.h>

// ---------------- conv1: [N,3,32,32] -> conv5x5(6) -> relu -> pool2 -> [N,6,14,14]
__global__ __launch_bounds__(256) void k_conv1(const float* __restrict__ x,
    const float* __restrict__ W1, const float* __restrict__ b1,
    float* __restrict__ h1) {
  __shared__ float img[3072];        // [3][32][32]
  __shared__ float wl[600];          // [ci*25+ky*5+kx][8] co padded to 8
  __shared__ float bs[8];
  const int t = threadIdx.x;
  const int n = blockIdx.x;
  const float4* src = (const float4*)(x + (size_t)n * 3072);
  float4* d4 = (float4*)img;
#pragma unroll
  for (int i = 0; i < 3; i++) d4[t + 256 * i] = src[t + 256 * i];
  for (int i = t; i < 450; i += 256) {
    int co = i / 75, r = i % 75;
    wl[r * 8 + co] = W1[i];
  }
  for (int i = t; i < 75; i += 256) { wl[i * 8 + 6] = 0.f; wl[i * 8 + 7] = 0.f; }
  if (t < 6) bs[t] = b1[t];
  __syncthreads();
  if (t < 196) {
    const int ph = t / 14, pw = t % 14;
    const int y0 = 2 * ph, x0 = 2 * pw;
    float acc[4][6];
#pragma unroll
    for (int p = 0; p < 4; p++)
#pragma unroll
      for (int c = 0; c < 6; c++) acc[p][c] = 0.f;
#pragma unroll
    for (int ci = 0; ci < 3; ci++) {
      float pz[6][6];
      const float* ib = img + ci * 1024 + y0 * 32 + x0;
#pragma unroll
      for (int r = 0; r < 6; r++)
#pragma unroll
        for (int c = 0; c < 6; c++) pz[r][c] = ib[r * 32 + c];
      const float* wb = wl + ci * 200;
#pragma unroll
      for (int ky = 0; ky < 5; ky++)
#pragma unroll
        for (int kx = 0; kx < 5; kx++) {
          const float* wv = wb + (ky * 5 + kx) * 8;
          const float i00 = pz[ky][kx], i01 = pz[ky][kx + 1];
          const float i10 = pz[ky + 1][kx], i11 = pz[ky + 1][kx + 1];
#pragma unroll
          for (int c = 0; c < 6; c++) {
            const float w = wv[c];
            acc[0][c] += w * i00;
            acc[1][c] += w * i01;
            acc[2][c] += w * i10;
            acc[3][c] += w * i11;
          }
        }
    }
    const size_t ob = (size_t)n * 1176 + t;
#pragma unroll
    for (int c = 0; c < 6; c++) {
      float m = fmaxf(fmaxf(acc[0][c], acc[1][c]), fmaxf(acc[2][c], acc[3][c]));
      h1[ob + c * 196] = fmaxf(m + bs[c], 0.f);
    }
  }
}

// ---------------- conv2: [N,6,14,14] -> conv5x5(16) -> relu -> pool2 -> [N,16,5,5]=[N,400]
__global__ __launch_bounds__(256) void k_conv2(const float* __restrict__ h1,
    const float* __restrict__ W2, const float* __restrict__ b2,
    float* __restrict__ h2) {
  __shared__ float in[10 * 1176];
  __shared__ float wl[2400];     // [ci*25+kk][16]
  __shared__ float bs[16];
  const int t = threadIdx.x;
  const int n0 = blockIdx.x * 10;
  const int nimg = min(10, 8192 - n0);
  const int nf4 = nimg * 294;    // 1176/4
  const float4* src = (const float4*)(h1 + (size_t)n0 * 1176);
  float4* d4 = (float4*)in;
  for (int i = t; i < nf4; i += 256) d4[i] = src[i];
  for (int i = t; i < 2400; i += 256) {
    int r = i >> 4, co = i & 15;
    wl[i] = W2[co * 150 + r];
  }
  if (t < 16) bs[t] = b2[t];
  __syncthreads();
  const int isub = t / 25, pos = t % 25;
  if (isub < nimg) {
    const int ph = pos / 5, pw = pos % 5;
    const int y0 = 2 * ph, x0 = 2 * pw;
    float acc[4][16];
#pragma unroll
    for (int p = 0; p < 4; p++)
#pragma unroll
      for (int c = 0; c < 16; c++) acc[p][c] = 0.f;
#pragma unroll
    for (int ci = 0; ci < 6; ci++) {
      float pz[6][6];
      const float* ib = in + isub * 1176 + ci * 196 + y0 * 14 + x0;
#pragma unroll
      for (int r = 0; r < 6; r++)
#pragma unroll
        for (int c = 0; c < 6; c++) pz[r][c] = ib[r * 14 + c];
#pragma unroll
      for (int kk = 0; kk < 25; kk++) {
        const int ky = kk / 5, kx = kk % 5;
        const float* wv = wl + (ci * 25 + kk) * 16;
        const float i00 = pz[ky][kx], i01 = pz[ky][kx + 1];
        const float i10 = pz[ky + 1][kx], i11 = pz[ky + 1][kx + 1];
#pragma unroll
        for (int c = 0; c < 16; c++) {
          const float w = wv[c];
          acc[0][c] += w * i00;
          acc[1][c] += w * i01;
          acc[2][c] += w * i10;
          acc[3][c] += w * i11;
        }
      }
    }
    const size_t ob = (size_t)(n0 + isub) * 400 + pos;
#pragma unroll
    for (int c = 0; c < 16; c++) {
      float m = fmaxf(fmaxf(acc[0][c], acc[1][c]), fmaxf(acc[2][c], acc[3][c]));
      h2[ob + c * 25] = fmaxf(m + bs[c], 0.f);
    }
  }
}

// ---------------- fc1: [N,400] @ [120,400]^T + b, relu -> [N,120]
__global__ __launch_bounds__(256) void k_fc1(const float* __restrict__ h2,
    const float* __restrict__ Wf1, const float* __restrict__ bf1,
    float* __restrict__ h3) {
  __shared__ float At[40 * 65];   // [k][row pad 65], 64 rows
  __shared__ float Bt[40 * 120];  // [k][col]
  const int t = threadIdx.x;
  const int row0 = blockIdx.x * 64;
  const int rowg = t >> 3, colg = t & 7;
  const int r0 = rowg * 2, c0 = colg * 15;
  float acc[2][15];
#pragma unroll
  for (int r = 0; r < 2; r++)
#pragma unroll
    for (int j = 0; j < 15; j++) acc[r][j] = 0.f;
  for (int k0 = 0; k0 < 400; k0 += 40) {
    __syncthreads();
    for (int i = t; i < 640; i += 256) {
      int row = i / 10, kq = i % 10;
      float4 v = *(const float4*)(h2 + (size_t)(row0 + row) * 400 + k0 + kq * 4);
      At[(kq * 4 + 0) * 65 + row] = v.x;
      At[(kq * 4 + 1) * 65 + row] = v.y;
      At[(kq * 4 + 2) * 65 + row] = v.z;
      At[(kq * 4 + 3) * 65 + row] = v.w;
    }
    for (int i = t; i < 1200; i += 256) {
      int kq = i / 120, c = i % 120;
      float4 v = *(const float4*)(Wf1 + (size_t)c * 400 + k0 + kq * 4);
      Bt[(kq * 4 + 0) * 120 + c] = v.x;
      Bt[(kq * 4 + 1) * 120 + c] = v.y;
      Bt[(kq * 4 + 2) * 120 + c] = v.z;
      Bt[(kq * 4 + 3) * 120 + c] = v.w;
    }
    __syncthreads();
#pragma unroll 4
    for (int k = 0; k < 40; k++) {
      const float a0 = At[k * 65 + r0];
      const float a1 = At[k * 65 + r0 + 1];
      float b[15];
#pragma unroll
      for (int j = 0; j < 15; j++) b[j] = Bt[k * 120 + c0 + j];
#pragma unroll
      for (int j = 0; j < 15; j++) {
        acc[0][j] += a0 * b[j];
        acc[1][j] += a1 * b[j];
      }
    }
  }
#pragma unroll
  for (int r = 0; r < 2; r++)
#pragma unroll
    for (int j = 0; j < 15; j++) {
      h3[(size_t)(row0 + r0 + r) * 120 + c0 + j] =
          fmaxf(acc[r][j] + bf1[c0 + j], 0.f);
    }
}

// ---------------- fc2 (relu) fused with GAT projection: z=h@Wg^T, el=z@al, er=z@ar
__global__ __launch_bounds__(256) void k_fc2z(const float* __restrict__ h3,
    const float* __restrict__ Wf2, const float* __restrict__ bf2,
    const float* __restrict__ Wg, const float* __restrict__ al,
    const float* __restrict__ ar, float* __restrict__ z,
    float* __restrict__ el, float* __restrict__ er) {
  __shared__ float At[60 * 33];   // [k][row pad 33], 32 rows
  __shared__ float Bt[60 * 88];   // [k][col pad 88], 84 real
  __shared__ float ht[32 * 84];
  __shared__ float zt[32 * 10];
  __shared__ float WgS[840];
  __shared__ float alS[10], arS[10];
  const int t = threadIdx.x;
  const int row0 = blockIdx.x * 32;
  const int rowg = t >> 3;        // row (0..31)
  const int c0 = (t & 7) * 11;    // 8 col groups x 11
  float acc[11];
#pragma unroll
  for (int j = 0; j < 11; j++) acc[j] = 0.f;
  for (int i = t; i < 840; i += 256) WgS[i] = Wg[i];
  if (t < 10) { alS[t] = al[t]; arS[t] = ar[t]; }
  for (int k0 = 0; k0 < 120; k0 += 60) {
    __syncthreads();
    for (int i = t; i < 480; i += 256) {
      int row = i / 15, kq = i % 15;
      float4 v = *(const float4*)(h3 + (size_t)(row0 + row) * 120 + k0 + kq * 4);
      At[(kq * 4 + 0) * 33 + row] = v.x;
      At[(kq * 4 + 1) * 33 + row] = v.y;
      At[(kq * 4 + 2) * 33 + row] = v.z;
      At[(kq * 4 + 3) * 33 + row] = v.w;
    }
    for (int i = t; i < 1320; i += 256) {
      int kq = i / 88, c = i % 88;
      float4 v = make_float4(0.f, 0.f, 0.f, 0.f);
      if (c < 84) v = *(const float4*)(Wf2 + (size_t)c * 120 + k0 + kq * 4);
      Bt[(kq * 4 + 0) * 88 + c] = v.x;
      Bt[(kq * 4 + 1) * 88 + c] = v.y;
      Bt[(kq * 4 + 2) * 88 + c] = v.z;
      Bt[(kq * 4 + 3) * 88 + c] = v.w;
    }
    __syncthreads();
#pragma unroll 4
    for (int k = 0; k < 60; k++) {
      const float a = At[k * 33 + rowg];
#pragma unroll
      for (int j = 0; j < 11; j++) acc[j] += a * Bt[k * 88 + c0 + j];
    }
  }
  __syncthreads();
#pragma unroll
  for (int j = 0; j < 11; j++) {
    const int c = c0 + j;
    if (c < 84) ht[rowg * 84 + c] = fmaxf(acc[j] + bf2[c], 0.f);
  }
  __syncthreads();
  for (int d = t; d < 320; d += 256) {
    const int r = d / 10, co = d % 10;
    float s = 0.f;
    for (int k = 0; k < 84; k++) s += ht[r * 84 + k] * WgS[co * 84 + k];
    zt[d] = s;
  }
  __syncthreads();
  if (t < 32) {
    float zl[10];
#pragma unroll
    for (int d = 0; d < 10; d++) zl[d] = zt[t * 10 + d];
    float ev = 0.f, rv = 0.f;
#pragma unroll
    for (int d = 0; d < 10; d++) { ev += zl[d] * alS[d]; rv += zl[d] * arS[d]; }
    const int gi = row0 + t;
#pragma unroll
    for (int d = 0; d < 10; d++) z[(size_t)gi * 10 + d] = zl[d];
    el[gi] = ev;
    er[gi] = rv;
  }
}

// ---------------- max over el
__global__ __launch_bounds__(256) void k_elmax(const float* __restrict__ el,
                                               float* __restrict__ out) {
  __shared__ float red[4];
  const int t = threadIdx.x;
  float m = -1e30f;
  for (int i = t; i < 8192; i += 256) m = fmaxf(m, el[i]);
#pragma unroll
  for (int off = 32; off > 0; off >>= 1) m = fmaxf(m, __shfl_down(m, off, 64));
  if ((t & 63) == 0) red[t >> 6] = m;
  __syncthreads();
  if (t == 0) out[0] = fmaxf(fmaxf(red[0], red[1]), fmaxf(red[2], red[3]));
}

// ---------------- attention partials: dst i per thread, j-range split 4-way
__global__ __launch_bounds__(256) void k_attn(const float* __restrict__ z,
    const float* __restrict__ el, const float* __restrict__ er,
    const float* __restrict__ elmax, float* __restrict__ part) {
  __shared__ float els[256];
  __shared__ float zs[256 * 10];
  const int t = threadIdx.x;
  const int i = blockIdx.x * 256 + t;
  const int split = blockIdx.y;
  const float eri = er[i];
  const float mx = elmax[0];
  const float s0 = eri + mx;
  const float mi = fmaxf(s0, 0.2f * s0);   // leaky_relu(s) = max(s, 0.2 s)
  float num[10];
#pragma unroll
  for (int d = 0; d < 10; d++) num[d] = 0.f;
  float den = 0.f;
  const int jbase = split * 2048;
  for (int j0 = 0; j0 < 2048; j0 += 256) {
    __syncthreads();
    els[t] = el[jbase + j0 + t];
    const float* zsrc = z + (size_t)(jbase + j0) * 10;
#pragma unroll
    for (int q = 0; q < 10; q++) zs[t + 256 * q] = zsrc[t + 256 * q];
    __syncthreads();
    for (int jj = 0; jj < 256; jj++) {
      const float s2 = eri + els[jj];
      const float lr = fmaxf(s2, 0.2f * s2);
      const float w = __expf(lr - mi);
      den += w;
      const float* zp = zs + jj * 10;
#pragma unroll
      for (int d = 0; d < 10; d++) num[d] += w * zp[d];
    }
  }
  float* pp = part + ((size_t)split * 8192 + i) * 12;
#pragma unroll
  for (int d = 0; d < 10; d++) pp[d] = num[d];
  pp[10] = den;
}

// ---------------- combine partials, divide, add bias
__global__ __launch_bounds__(256) void k_final(const float* __restrict__ part,
    const float* __restrict__ bg, float* __restrict__ out) {
  const int i = blockIdx.x * 256 + threadIdx.x;
  float num[10];
#pragma unroll
  for (int d = 0; d < 10; d++) num[d] = 0.f;
  float den = 0.f;
#pragma unroll
  for (int s = 0; s < 4; s++) {
    const float* pp = part + ((size_t)s * 8192 + i) * 12;
#pragma unroll
    for (int d = 0; d < 10; d++) num[d] += pp[d];
    den += pp[10];
  }
  const float inv = 1.f / den;
#pragma unroll
  for (int d = 0; d < 10; d++) out[(size_t)i * 10 + d] = num[d] * inv + bg[d];
}

extern "C" void kernel_launch(void* const* d_in, const int* in_sizes, int n_in,
                              void* d_out, int out_size, void* d_ws, size_t ws_size,
                              hipStream_t stream) {
  const float* x   = (const float*)d_in[0];
  const float* W1  = (const float*)d_in[1];
  const float* b1  = (const float*)d_in[2];
  const float* W2  = (const float*)d_in[3];
  const float* b2  = (const float*)d_in[4];
  const float* Wf1 = (const float*)d_in[5];
  const float* bf1 = (const float*)d_in[6];
  const float* Wf2 = (const float*)d_in[7];
  const float* bf2 = (const float*)d_in[8];
  const float* Wg  = (const float*)d_in[9];
  const float* al  = (const float*)d_in[10];
  const float* ar  = (const float*)d_in[11];
  const float* bg  = (const float*)d_in[12];
  float* out = (float*)d_out;

  float* ws  = (float*)d_ws;
  float* h1  = ws;                          // 8192*1176
  float* h2  = h1 + (size_t)8192 * 1176;    // 8192*400
  float* h3  = h2 + (size_t)8192 * 400;     // 8192*120
  float* z   = h3 + (size_t)8192 * 120;     // 8192*10
  float* el  = z + (size_t)8192 * 10;       // 8192
  float* er  = el + 8192;                   // 8192
  float* emx = er + 8192;                   // 16 (1 used)
  float* part = emx + 16;                   // 4*8192*12

  k_conv1<<<8192, 256, 0, stream>>>(x, W1, b1, h1);
  k_conv2<<<820, 256, 0, stream>>>(h1, W2, b2, h2);
  k_fc1<<<128, 256, 0, stream>>>(h2, Wf1, bf1, h3);
  k_fc2z<<<256, 256, 0, stream>>>(h3, Wf2, bf2, Wg, al, ar, z, el, er);
  k_elmax<<<1, 256, 0, stream>>>(el, emx);
  dim3 ag(32, 4);
  k_attn<<<ag, 256, 0, stream>>>(z, el, er, emx, part);
  k_final<<<32, 256, 0, stream>>>(part, bg, out);
}

// Round 2
// 400.645 us; speedup vs baseline: 1.1443x; 1.1443x over previous
//
#include <hip/hip_runtime.h>
#include <hip/hip_bf16.h>

#define PZ(r, c) (((c) & 1) ? pz2[r][(c) >> 1].y : pz2[r][(c) >> 1].x)

// ---------------- conv1: [N,3,32,32] -> conv5x5(6) -> relu -> pool2 -> [N,6,14,14]
__global__ __launch_bounds__(256) void k_conv1(const float* __restrict__ x,
    const float* __restrict__ W1, const float* __restrict__ b1,
    float* __restrict__ h1) {
  __shared__ __align__(16) float img[3072];  // [3][32][32]
  __shared__ __align__(16) float wl[600];    // [ci*25+kk][8] co padded to 8
  __shared__ float bs[8];
  const int t = threadIdx.x;
  const int n = blockIdx.x;
  const float4* src = (const float4*)(x + (size_t)n * 3072);
  float4* d4 = (float4*)img;
#pragma unroll
  for (int i = 0; i < 3; i++) d4[t + 256 * i] = src[t + 256 * i];
  for (int i = t; i < 450; i += 256) {
    int co = i / 75, r = i % 75;
    wl[r * 8 + co] = W1[i];
  }
  if (t < 6) bs[t] = b1[t];
  __syncthreads();
  if (t < 196) {
    const int ph = t / 14, pw = t % 14;
    const int y0 = 2 * ph, x0 = 2 * pw;
    float acc[4][6];
#pragma unroll
    for (int p = 0; p < 4; p++)
#pragma unroll
      for (int c = 0; c < 6; c++) acc[p][c] = 0.f;
    for (int ci = 0; ci < 3; ci++) {
      float2 pz2[6][3];
      const float* ib = img + ci * 1024 + y0 * 32 + x0;  // even offset -> 8B aligned
#pragma unroll
      for (int r = 0; r < 6; r++)
#pragma unroll
        for (int q = 0; q < 3; q++) pz2[r][q] = *(const float2*)(ib + r * 32 + q * 2);
      const float* wb = wl + ci * 200;
#pragma unroll
      for (int kk = 0; kk < 25; kk++) {
        const int ky = kk / 5, kx = kk % 5;
        const float2* wv = (const float2*)(wb + kk * 8);
        const float2 w01 = wv[0], w23 = wv[1], w45 = wv[2];
        const float w[6] = {w01.x, w01.y, w23.x, w23.y, w45.x, w45.y};
        const float i00 = PZ(ky, kx), i01 = PZ(ky, kx + 1);
        const float i10 = PZ(ky + 1, kx), i11 = PZ(ky + 1, kx + 1);
#pragma unroll
        for (int c = 0; c < 6; c++) {
          acc[0][c] += w[c] * i00;
          acc[1][c] += w[c] * i01;
          acc[2][c] += w[c] * i10;
          acc[3][c] += w[c] * i11;
        }
      }
    }
    const size_t ob = (size_t)n * 1176 + t;
#pragma unroll
    for (int c = 0; c < 6; c++) {
      float m = fmaxf(fmaxf(acc[0][c], acc[1][c]), fmaxf(acc[2][c], acc[3][c]));
      h1[ob + c * 196] = fmaxf(m + bs[c], 0.f);
    }
  }
}

// ---------------- conv2: [N,6,14,14] -> conv5x5(16) -> relu -> pool2 -> [N,16,5,5]
// 5 images/block, co split 2-way (8 per thread): 250/256 lanes active.
__global__ __launch_bounds__(256) void k_conv2(const float* __restrict__ h1,
    const float* __restrict__ W2, const float* __restrict__ b2,
    float* __restrict__ h2) {
  __shared__ __align__(16) float in[5 * 1176];
  __shared__ __align__(16) float wl[2400];  // [ci*25+kk][16]
  __shared__ float bs[16];
  const int t = threadIdx.x;
  const int n0 = blockIdx.x * 5;
  const int nimg = min(5, 8192 - n0);
  const int nf4 = nimg * 294;  // 1176/4
  const float4* src = (const float4*)(h1 + (size_t)n0 * 1176);
  float4* d4 = (float4*)in;
  for (int i = t; i < nf4; i += 256) d4[i] = src[i];
  for (int i = t; i < 2400; i += 256) {
    int r = i >> 4, co = i & 15;
    wl[i] = W2[co * 150 + r];
  }
  if (t < 16) bs[t] = b2[t];
  __syncthreads();
  const int isub = t / 50, half = (t % 50) / 25, pos = t % 25;
  if (isub < nimg) {
    const int ph = pos / 5, pw = pos % 5;
    const int y0 = 2 * ph, x0 = 2 * pw;
    const int cbase = half * 8;
    float acc[4][8];
#pragma unroll
    for (int p = 0; p < 4; p++)
#pragma unroll
      for (int c = 0; c < 8; c++) acc[p][c] = 0.f;
    for (int ci = 0; ci < 6; ci++) {
      float2 pz2[6][3];
      const float* ib = in + isub * 1176 + ci * 196 + y0 * 14 + x0;  // even
#pragma unroll
      for (int r = 0; r < 6; r++)
#pragma unroll
        for (int q = 0; q < 3; q++) pz2[r][q] = *(const float2*)(ib + r * 14 + q * 2);
      const float* wb = wl + ci * 400 + cbase;
#pragma unroll
      for (int kk = 0; kk < 25; kk++) {
        const int ky = kk / 5, kx = kk % 5;
        const float4* wv = (const float4*)(wb + kk * 16);
        const float4 wa = wv[0], wbv = wv[1];
        const float w[8] = {wa.x, wa.y, wa.z, wa.w, wbv.x, wbv.y, wbv.z, wbv.w};
        const float i00 = PZ(ky, kx), i01 = PZ(ky, kx + 1);
        const float i10 = PZ(ky + 1, kx), i11 = PZ(ky + 1, kx + 1);
#pragma unroll
        for (int c = 0; c < 8; c++) {
          acc[0][c] += w[c] * i00;
          acc[1][c] += w[c] * i01;
          acc[2][c] += w[c] * i10;
          acc[3][c] += w[c] * i11;
        }
      }
    }
    const size_t ob = (size_t)(n0 + isub) * 400 + pos;
#pragma unroll
    for (int c = 0; c < 8; c++) {
      float m = fmaxf(fmaxf(acc[0][c], acc[1][c]), fmaxf(acc[2][c], acc[3][c]));
      h2[ob + (cbase + c) * 25] = fmaxf(m + bs[cbase + c], 0.f);
    }
  }
}

// ---------------- fc1: [N,400] @ [120,400]^T + b, relu -> [N,120]
__global__ __launch_bounds__(256) void k_fc1(const float* __restrict__ h2,
    const float* __restrict__ Wf1, const float* __restrict__ bf1,
    float* __restrict__ h3) {
  __shared__ __align__(16) float At[40 * 65];   // [k][row pad 65]
  __shared__ __align__(16) float Bt[40 * 120];  // [k][col]
  const int t = threadIdx.x;
  const int row0 = blockIdx.x * 64;
  const int rowg = t >> 3, colg = t & 7;
  const int r0 = rowg * 2, c0 = colg * 15;
  float acc[2][15];
#pragma unroll
  for (int r = 0; r < 2; r++)
#pragma unroll
    for (int j = 0; j < 15; j++) acc[r][j] = 0.f;
  for (int k0 = 0; k0 < 400; k0 += 40) {
    __syncthreads();
    for (int i = t; i < 640; i += 256) {
      int row = i / 10, kq = i % 10;
      float4 v = *(const float4*)(h2 + (size_t)(row0 + row) * 400 + k0 + kq * 4);
      At[(kq * 4 + 0) * 65 + row] = v.x;
      At[(kq * 4 + 1) * 65 + row] = v.y;
      At[(kq * 4 + 2) * 65 + row] = v.z;
      At[(kq * 4 + 3) * 65 + row] = v.w;
    }
    for (int i = t; i < 1200; i += 256) {
      int kq = i / 120, c = i % 120;
      float4 v = *(const float4*)(Wf1 + (size_t)c * 400 + k0 + kq * 4);
      Bt[(kq * 4 + 0) * 120 + c] = v.x;
      Bt[(kq * 4 + 1) * 120 + c] = v.y;
      Bt[(kq * 4 + 2) * 120 + c] = v.z;
      Bt[(kq * 4 + 3) * 120 + c] = v.w;
    }
    __syncthreads();
#pragma unroll 4
    for (int k = 0; k < 40; k++) {
      const float a0 = At[k * 65 + r0];
      const float a1 = At[k * 65 + r0 + 1];
      float b[15];
#pragma unroll
      for (int j = 0; j < 15; j++) b[j] = Bt[k * 120 + c0 + j];
#pragma unroll
      for (int j = 0; j < 15; j++) {
        acc[0][j] += a0 * b[j];
        acc[1][j] += a1 * b[j];
      }
    }
  }
#pragma unroll
  for (int r = 0; r < 2; r++)
#pragma unroll
    for (int j = 0; j < 15; j++) {
      h3[(size_t)(row0 + r0 + r) * 120 + c0 + j] =
          fmaxf(acc[r][j] + bf1[c0 + j], 0.f);
    }
}

// ---------------- fc2 (relu) fused with GAT projection
__global__ __launch_bounds__(256) void k_fc2z(const float* __restrict__ h3,
    const float* __restrict__ Wf2, const float* __restrict__ bf2,
    const float* __restrict__ Wg, const float* __restrict__ al,
    const float* __restrict__ ar, float* __restrict__ z,
    float* __restrict__ el, float* __restrict__ er) {
  __shared__ __align__(16) float At[60 * 33];
  __shared__ __align__(16) float Bt[60 * 88];
  __shared__ float ht[32 * 84];
  __shared__ float zt[32 * 10];
  __shared__ float WgS[840];
  __shared__ float alS[10], arS[10];
  const int t = threadIdx.x;
  const int row0 = blockIdx.x * 32;
  const int rowg = t >> 3;
  const int c0 = (t & 7) * 11;
  float acc[11];
#pragma unroll
  for (int j = 0; j < 11; j++) acc[j] = 0.f;
  for (int i = t; i < 840; i += 256) WgS[i] = Wg[i];
  if (t < 10) { alS[t] = al[t]; arS[t] = ar[t]; }
  for (int k0 = 0; k0 < 120; k0 += 60) {
    __syncthreads();
    for (int i = t; i < 480; i += 256) {
      int row = i / 15, kq = i % 15;
      float4 v = *(const float4*)(h3 + (size_t)(row0 + row) * 120 + k0 + kq * 4);
      At[(kq * 4 + 0) * 33 + row] = v.x;
      At[(kq * 4 + 1) * 33 + row] = v.y;
      At[(kq * 4 + 2) * 33 + row] = v.z;
      At[(kq * 4 + 3) * 33 + row] = v.w;
    }
    for (int i = t; i < 1320; i += 256) {
      int kq = i / 88, c = i % 88;
      float4 v = make_float4(0.f, 0.f, 0.f, 0.f);
      if (c < 84) v = *(const float4*)(Wf2 + (size_t)c * 120 + k0 + kq * 4);
      Bt[(kq * 4 + 0) * 88 + c] = v.x;
      Bt[(kq * 4 + 1) * 88 + c] = v.y;
      Bt[(kq * 4 + 2) * 88 + c] = v.z;
      Bt[(kq * 4 + 3) * 88 + c] = v.w;
    }
    __syncthreads();
#pragma unroll 4
    for (int k = 0; k < 60; k++) {
      const float a = At[k * 33 + rowg];
#pragma unroll
      for (int j = 0; j < 11; j++) acc[j] += a * Bt[k * 88 + c0 + j];
    }
  }
  __syncthreads();
#pragma unroll
  for (int j = 0; j < 11; j++) {
    const int c = c0 + j;
    if (c < 84) ht[rowg * 84 + c] = fmaxf(acc[j] + bf2[c], 0.f);
  }
  __syncthreads();
  for (int d = t; d < 320; d += 256) {
    const int r = d / 10, co = d % 10;
    float s = 0.f;
    for (int k = 0; k < 84; k++) s += ht[r * 84 + k] * WgS[co * 84 + k];
    zt[d] = s;
  }
  __syncthreads();
  if (t < 32) {
    float zl[10];
#pragma unroll
    for (int d = 0; d < 10; d++) zl[d] = zt[t * 10 + d];
    float ev = 0.f, rv = 0.f;
#pragma unroll
    for (int d = 0; d < 10; d++) { ev += zl[d] * alS[d]; rv += zl[d] * arS[d]; }
    const int gi = row0 + t;
#pragma unroll
    for (int d = 0; d < 10; d++) z[(size_t)gi * 10 + d] = zl[d];
    el[gi] = ev;
    er[gi] = rv;
  }
}

// ---------------- max over el
__global__ __launch_bounds__(256) void k_elmax(const float* __restrict__ el,
                                               float* __restrict__ out) {
  __shared__ float red[4];
  const int t = threadIdx.x;
  float m = -1e30f;
  for (int i = t; i < 8192; i += 256) m = fmaxf(m, el[i]);
#pragma unroll
  for (int off = 32; off > 0; off >>= 1) m = fmaxf(m, __shfl_down(m, off, 64));
  if ((t & 63) == 0) red[t >> 6] = m;
  __syncthreads();
  if (t == 0) out[0] = fmaxf(fmaxf(red[0], red[1]), fmaxf(red[2], red[3]));
}

// ---------------- attention partials: dst i per thread, 32 j-splits of 256
// zs row: [z0..z9, el, pad] stride 12 -> 3x b128 per edge
__global__ __launch_bounds__(256) void k_attn(const float* __restrict__ z,
    const float* __restrict__ el, const float* __restrict__ er,
    const float* __restrict__ elmax, float* __restrict__ part) {
  __shared__ __align__(16) float zs[256 * 12];
  const int t = threadIdx.x;
  const int i = blockIdx.x * 256 + t;
  const int split = blockIdx.y;
  const int jbase = split * 256;
  // stage z (coalesced over flat index) and el
  for (int idx = t; idx < 2560; idx += 256) {
    int jj = idx / 10, d = idx % 10;
    zs[jj * 12 + d] = z[(size_t)jbase * 10 + idx];
  }
  zs[t * 12 + 10] = el[jbase + t];
  const float eri = er[i];
  const float mx = elmax[0];
  const float s0 = eri + mx;
  const float mi = fmaxf(s0, 0.2f * s0);  // leaky_relu monotone -> row max
  float num[10];
#pragma unroll
  for (int d = 0; d < 10; d++) num[d] = 0.f;
  float den = 0.f;
  __syncthreads();
  for (int jj = 0; jj < 256; jj++) {
    const float4 za = *(const float4*)(zs + jj * 12);
    const float4 zb = *(const float4*)(zs + jj * 12 + 4);
    const float2 zc = *(const float2*)(zs + jj * 12 + 8);
    const float elj = zs[jj * 12 + 10];
    const float s2 = eri + elj;
    const float lr = fmaxf(s2, 0.2f * s2);
    const float w = __expf(lr - mi);
    den += w;
    num[0] += w * za.x; num[1] += w * za.y; num[2] += w * za.z; num[3] += w * za.w;
    num[4] += w * zb.x; num[5] += w * zb.y; num[6] += w * zb.z; num[7] += w * zb.w;
    num[8] += w * zc.x; num[9] += w * zc.y;
  }
  // planar partials: part[(split*12 + d)*8192 + i] (coalesced)
  float* pp = part + (size_t)split * 12 * 8192 + i;
#pragma unroll
  for (int d = 0; d < 10; d++) pp[d * 8192] = num[d];
  pp[10 * 8192] = den;
}

// ---------------- combine partials, divide, add bias
__global__ __launch_bounds__(256) void k_final(const float* __restrict__ part,
    const float* __restrict__ bg, float* __restrict__ out) {
  const int i = blockIdx.x * 256 + threadIdx.x;
  float num[10];
#pragma unroll
  for (int d = 0; d < 10; d++) num[d] = 0.f;
  float den = 0.f;
  for (int s = 0; s < 32; s++) {
    const float* pp = part + (size_t)s * 12 * 8192 + i;
#pragma unroll
    for (int d = 0; d < 10; d++) num[d] += pp[d * 8192];
    den += pp[10 * 8192];
  }
  const float inv = 1.f / den;
#pragma unroll
  for (int d = 0; d < 10; d++) out[(size_t)i * 10 + d] = num[d] * inv + bg[d];
}

extern "C" void kernel_launch(void* const* d_in, const int* in_sizes, int n_in,
                              void* d_out, int out_size, void* d_ws, size_t ws_size,
                              hipStream_t stream) {
  const float* x   = (const float*)d_in[0];
  const float* W1  = (const float*)d_in[1];
  const float* b1  = (const float*)d_in[2];
  const float* W2  = (const float*)d_in[3];
  const float* b2  = (const float*)d_in[4];
  const float* Wf1 = (const float*)d_in[5];
  const float* bf1 = (const float*)d_in[6];
  const float* Wf2 = (const float*)d_in[7];
  const float* bf2 = (const float*)d_in[8];
  const float* Wg  = (const float*)d_in[9];
  const float* al  = (const float*)d_in[10];
  const float* ar  = (const float*)d_in[11];
  const float* bg  = (const float*)d_in[12];
  float* out = (float*)d_out;

  float* ws  = (float*)d_ws;
  float* h1  = ws;                          // 8192*1176
  float* h2  = h1 + (size_t)8192 * 1176;    // 8192*400
  float* h3  = h2 + (size_t)8192 * 400;     // 8192*120
  float* z   = h3 + (size_t)8192 * 120;     // 8192*10
  float* el  = z + (size_t)8192 * 10;       // 8192
  float* er  = el + 8192;                   // 8192
  float* emx = er + 8192;                   // 16 (1 used)
  float* part = h1;                         // aliases h1 (dead after conv2): 32*12*8192

  k_conv1<<<8192, 256, 0, stream>>>(x, W1, b1, h1);
  k_conv2<<<1639, 256, 0, stream>>>(h1, W2, b2, h2);
  k_fc1<<<128, 256, 0, stream>>>(h2, Wf1, bf1, h3);
  k_fc2z<<<256, 256, 0, stream>>>(h3, Wf2, bf2, Wg, al, ar, z, el, er);
  k_elmax<<<1, 256, 0, stream>>>(el, emx);
  dim3 ag(32, 32);
  k_attn<<<ag, 256, 0, stream>>>(z, el, er, emx, part);
  k_final<<<32, 256, 0, stream>>>(part, bg, out);
}

// Round 3
// 330.240 us; speedup vs baseline: 1.3882x; 1.2132x over previous
//
#include <hip/hip_runtime.h>
#include <hip/hip_bf16.h>

typedef _Float16 half8 __attribute__((ext_vector_type(8)));
typedef _Float16 half2v __attribute__((ext_vector_type(2)));
typedef float floatx4 __attribute__((ext_vector_type(4)));

#define PZ(r, c) (((c) & 1) ? pz2[r][(c) >> 1].y : pz2[r][(c) >> 1].x)

// ---------------- prep: convert/pad weights to f16
// w1f: [128][416] (120x400 real), w2f: [96][128] (84x120), wgf: [16][96] (10x84)
__global__ __launch_bounds__(256) void k_prep(const float* __restrict__ Wf1,
    const float* __restrict__ Wf2, const float* __restrict__ Wg,
    _Float16* __restrict__ w1f, _Float16* __restrict__ w2f,
    _Float16* __restrict__ wgf) {
  const int i = blockIdx.x * 256 + threadIdx.x;
  if (i < 53248) {
    const int n = i / 416, k = i - n * 416;
    w1f[i] = (_Float16)((n < 120 && k < 400) ? Wf1[n * 400 + k] : 0.f);
  } else if (i < 65536) {
    const int j = i - 53248;
    const int n = j >> 7, k = j & 127;
    w2f[j] = (_Float16)((n < 84 && k < 120) ? Wf2[n * 120 + k] : 0.f);
  } else if (i < 67072) {
    const int g = i - 65536;
    const int n = g / 96, k = g - n * 96;
    wgf[g] = (_Float16)((n < 10 && k < 84) ? Wg[n * 84 + k] : 0.f);
  }
}

// ---------------- conv1: [N,3,32,32] -> conv5x5(6) -> relu -> pool2 -> f16 [N,6,14,14]
__global__ __launch_bounds__(256) void k_conv1(const float* __restrict__ x,
    const float* __restrict__ W1, const float* __restrict__ b1,
    _Float16* __restrict__ h1) {
  __shared__ __align__(16) float img[3072];  // [3][32][32]
  __shared__ __align__(16) float wl[600];    // [ci*25+kk][8] co padded to 8
  __shared__ float bs[8];
  const int t = threadIdx.x;
  const int n = blockIdx.x;
  const float4* src = (const float4*)(x + (size_t)n * 3072);
  float4* d4 = (float4*)img;
#pragma unroll
  for (int i = 0; i < 3; i++) d4[t + 256 * i] = src[t + 256 * i];
  for (int i = t; i < 450; i += 256) {
    int co = i / 75, r = i % 75;
    wl[r * 8 + co] = W1[i];
  }
  if (t < 6) bs[t] = b1[t];
  __syncthreads();
  if (t < 196) {
    const int ph = t / 14, pw = t % 14;
    const int y0 = 2 * ph, x0 = 2 * pw;
    float acc[4][6];
#pragma unroll
    for (int p = 0; p < 4; p++)
#pragma unroll
      for (int c = 0; c < 6; c++) acc[p][c] = 0.f;
    for (int ci = 0; ci < 3; ci++) {
      float2 pz2[6][3];
      const float* ib = img + ci * 1024 + y0 * 32 + x0;
#pragma unroll
      for (int r = 0; r < 6; r++)
#pragma unroll
        for (int q = 0; q < 3; q++) pz2[r][q] = *(const float2*)(ib + r * 32 + q * 2);
      const float* wb = wl + ci * 200;
#pragma unroll
      for (int kk = 0; kk < 25; kk++) {
        const int ky = kk / 5, kx = kk % 5;
        const float2* wv = (const float2*)(wb + kk * 8);
        const float2 w01 = wv[0], w23 = wv[1], w45 = wv[2];
        const float w[6] = {w01.x, w01.y, w23.x, w23.y, w45.x, w45.y};
        const float i00 = PZ(ky, kx), i01 = PZ(ky, kx + 1);
        const float i10 = PZ(ky + 1, kx), i11 = PZ(ky + 1, kx + 1);
#pragma unroll
        for (int c = 0; c < 6; c++) {
          acc[0][c] += w[c] * i00;
          acc[1][c] += w[c] * i01;
          acc[2][c] += w[c] * i10;
          acc[3][c] += w[c] * i11;
        }
      }
    }
    const size_t ob = (size_t)n * 1176 + t;
#pragma unroll
    for (int c = 0; c < 6; c++) {
      float m = fmaxf(fmaxf(acc[0][c], acc[1][c]), fmaxf(acc[2][c], acc[3][c]));
      h1[ob + c * 196] = (_Float16)fmaxf(m + bs[c], 0.f);
    }
  }
}

// ---------------- conv2: f16 [N,6,14,14] -> conv5x5(16) -> relu -> pool2 -> f16 [N][416]
// 5 images/block, co split 2-way (8 per thread): 250/256 lanes active.
__global__ __launch_bounds__(256) void k_conv2(const _Float16* __restrict__ h1,
    const float* __restrict__ W2, const float* __restrict__ b2,
    _Float16* __restrict__ h2) {
  __shared__ __align__(16) _Float16 in[5 * 1176];
  __shared__ __align__(16) float wl[2400];  // [ci*25+kk][16]
  __shared__ float bs[16];
  const int t = threadIdx.x;
  const int n0 = blockIdx.x * 5;
  const int nimg = min(5, 8192 - n0);
  const int nf4 = nimg * 147;  // 1176*2B/16
  const float4* src = (const float4*)(h1 + (size_t)n0 * 1176);
  float4* d4 = (float4*)in;
  for (int i = t; i < nf4; i += 256) d4[i] = src[i];
  for (int i = t; i < 2400; i += 256) {
    int r = i >> 4, co = i & 15;
    wl[i] = W2[co * 150 + r];
  }
  if (t < 16) bs[t] = b2[t];
  // zero k-pad of h2 rows [400..416)
  if (t < nimg * 16) h2[(size_t)(n0 + t / 16) * 416 + 400 + (t & 15)] = (_Float16)0.f;
  __syncthreads();
  const int isub = t / 50, half = (t % 50) / 25, pos = t % 25;
  if (isub < nimg) {
    const int ph = pos / 5, pw = pos % 5;
    const int y0 = 2 * ph, x0 = 2 * pw;
    const int cbase = half * 8;
    float acc[4][8];
#pragma unroll
    for (int p = 0; p < 4; p++)
#pragma unroll
      for (int c = 0; c < 8; c++) acc[p][c] = 0.f;
    for (int ci = 0; ci < 6; ci++) {
      float2 pz2[6][3];
      const _Float16* ib = in + isub * 1176 + ci * 196 + y0 * 14 + x0;  // even idx
#pragma unroll
      for (int r = 0; r < 6; r++)
#pragma unroll
        for (int q = 0; q < 3; q++) {
          half2v v = *(const half2v*)(ib + r * 14 + q * 2);
          pz2[r][q] = make_float2((float)v.x, (float)v.y);
        }
      const float* wb = wl + ci * 400 + cbase;
#pragma unroll
      for (int kk = 0; kk < 25; kk++) {
        const int ky = kk / 5, kx = kk % 5;
        const float4* wv = (const float4*)(wb + kk * 16);
        const float4 wa = wv[0], wbv = wv[1];
        const float w[8] = {wa.x, wa.y, wa.z, wa.w, wbv.x, wbv.y, wbv.z, wbv.w};
        const float i00 = PZ(ky, kx), i01 = PZ(ky, kx + 1);
        const float i10 = PZ(ky + 1, kx), i11 = PZ(ky + 1, kx + 1);
#pragma unroll
        for (int c = 0; c < 8; c++) {
          acc[0][c] += w[c] * i00;
          acc[1][c] += w[c] * i01;
          acc[2][c] += w[c] * i10;
          acc[3][c] += w[c] * i11;
        }
      }
    }
    const size_t ob = (size_t)(n0 + isub) * 416 + pos;
#pragma unroll
    for (int c = 0; c < 8; c++) {
      float m = fmaxf(fmaxf(acc[0][c], acc[1][c]), fmaxf(acc[2][c], acc[3][c]));
      h2[ob + (cbase + c) * 25] = (_Float16)fmaxf(m + bs[cbase + c], 0.f);
    }
  }
}

// ---------------- fused MLP via f16 MFMA: fc1(relu) -> fc2(relu) -> z -> el/er
// 32 rows/block. A/B fragments read directly from global (B is L2-hot).
// MFMA 16x16x32: A[m=lane&15][k=quad*8+j]; B[k=quad*8+j][n=lane&15];
// D col=lane&15, row=quad*4+reg.
__global__ __launch_bounds__(256) void k_mlp(
    const _Float16* __restrict__ h2,   // [8192][416]
    const _Float16* __restrict__ w1,   // [128][416]
    const float* __restrict__ bf1,     // [120]
    const _Float16* __restrict__ w2,   // [96][128]
    const float* __restrict__ bf2,     // [84]
    const _Float16* __restrict__ wg,   // [16][96]
    const float* __restrict__ al, const float* __restrict__ ar,
    float* __restrict__ z, float* __restrict__ el, float* __restrict__ er) {
  __shared__ __align__(16) _Float16 h3s[32 * 136];  // [row][k pad 136]
  __shared__ __align__(16) _Float16 h4s[32 * 104];  // [row][k pad 104]
  __shared__ float zs[32 * 17];
  const int t = threadIdx.x;
  const int w = t >> 6, lane = t & 63;
  const int l16 = lane & 15, q = lane >> 4;
  const int row0 = blockIdx.x * 32;
  // zero-init padded LDS tiles
  for (int i = t; i < 2176; i += 256) ((float*)h3s)[i] = 0.f;
  for (int i = t; i < 1664; i += 256) ((float*)h4s)[i] = 0.f;
  // ---- fc1: [32x400] @ [400x120] -> h3 tile
  const int rt = w & 1, cg = w >> 1;
  const int am = row0 + rt * 16 + l16;
  floatx4 acc[4];
#pragma unroll
  for (int ct = 0; ct < 4; ct++)
#pragma unroll
    for (int r = 0; r < 4; r++) acc[ct][r] = 0.f;
  const half8* Ag = (const half8*)(h2 + (size_t)am * 416 + q * 8);
  for (int kc = 0; kc < 13; kc++) {
    half8 a = Ag[kc * 4];
#pragma unroll
    for (int ct = 0; ct < 4; ct++) {
      const int n = cg * 64 + ct * 16 + l16;
      half8 b = *(const half8*)(w1 + (size_t)n * 416 + kc * 32 + q * 8);
      acc[ct] = __builtin_amdgcn_mfma_f32_16x16x32_f16(a, b, acc[ct], 0, 0, 0);
    }
  }
  __syncthreads();  // zero-init done; fc1 accs ready
#pragma unroll
  for (int ct = 0; ct < 4; ct++) {
    const int n = cg * 64 + ct * 16 + l16;
    if (n < 120) {
      const float bias = bf1[n];
#pragma unroll
      for (int r = 0; r < 4; r++) {
        const int rr = rt * 16 + q * 4 + r;
        h3s[rr * 136 + n] = (_Float16)fmaxf(acc[ct][r] + bias, 0.f);
      }
    }
  }
  __syncthreads();
  // ---- fc2: [32x120] @ [120x84] -> h4 tile
  const int cbase2 = (w >> 1) * 3;
  floatx4 acc2[3];
#pragma unroll
  for (int ct = 0; ct < 3; ct++)
#pragma unroll
    for (int r = 0; r < 4; r++) acc2[ct][r] = 0.f;
  const _Float16* A2 = h3s + (rt * 16 + l16) * 136 + q * 8;
  for (int kc = 0; kc < 4; kc++) {
    half8 a = *(const half8*)(A2 + kc * 32);
#pragma unroll
    for (int ct = 0; ct < 3; ct++) {
      const int n = (cbase2 + ct) * 16 + l16;
      half8 b = *(const half8*)(w2 + (size_t)n * 128 + kc * 32 + q * 8);
      acc2[ct] = __builtin_amdgcn_mfma_f32_16x16x32_f16(a, b, acc2[ct], 0, 0, 0);
    }
  }
  __syncthreads();
#pragma unroll
  for (int ct = 0; ct < 3; ct++) {
    const int n = (cbase2 + ct) * 16 + l16;
    if (n < 84) {
      const float bias = bf2[n];
#pragma unroll
      for (int r = 0; r < 4; r++) {
        const int rr = rt * 16 + q * 4 + r;
        h4s[rr * 104 + n] = (_Float16)fmaxf(acc2[ct][r] + bias, 0.f);
      }
    }
  }
  __syncthreads();
  // ---- z: [32x84] @ [84x10] (waves 0,1)
  if (w < 2) {
    floatx4 acc3;
#pragma unroll
    for (int r = 0; r < 4; r++) acc3[r] = 0.f;
    const _Float16* A3 = h4s + (w * 16 + l16) * 104 + q * 8;
    for (int kc = 0; kc < 3; kc++) {
      half8 a = *(const half8*)(A3 + kc * 32);
      half8 b = *(const half8*)(wg + (size_t)l16 * 96 + kc * 32 + q * 8);
      acc3 = __builtin_amdgcn_mfma_f32_16x16x32_f16(a, b, acc3, 0, 0, 0);
    }
#pragma unroll
    for (int r = 0; r < 4; r++) {
      const int rr = w * 16 + q * 4 + r;
      zs[rr * 17 + l16] = acc3[r];
      if (l16 < 10) z[(size_t)(row0 + rr) * 10 + l16] = acc3[r];
    }
  }
  __syncthreads();
  if (t < 32) {
    float e1 = 0.f, e2 = 0.f;
#pragma unroll
    for (int d = 0; d < 10; d++) {
      const float zv = zs[t * 17 + d];
      e1 += zv * al[d];
      e2 += zv * ar[d];
    }
    el[row0 + t] = e1;
    er[row0 + t] = e2;
  }
}

// ---------------- max over el
__global__ __launch_bounds__(256) void k_elmax(const float* __restrict__ el,
                                               float* __restrict__ out) {
  __shared__ float red[4];
  const int t = threadIdx.x;
  float m = -1e30f;
  for (int i = t; i < 8192; i += 256) m = fmaxf(m, el[i]);
#pragma unroll
  for (int off = 32; off > 0; off >>= 1) m = fmaxf(m, __shfl_down(m, off, 64));
  if ((t & 63) == 0) red[t >> 6] = m;
  __syncthreads();
  if (t == 0) out[0] = fmaxf(fmaxf(red[0], red[1]), fmaxf(red[2], red[3]));
}

// ---------------- attention partials: dst i per thread, 32 j-splits of 256
__global__ __launch_bounds__(256) void k_attn(const float* __restrict__ z,
    const float* __restrict__ el, const float* __restrict__ er,
    const float* __restrict__ elmax, float* __restrict__ part) {
  __shared__ __align__(16) float zsm[256 * 12];
  const int t = threadIdx.x;
  const int i = blockIdx.x * 256 + t;
  const int split = blockIdx.y;
  const int jbase = split * 256;
  for (int idx = t; idx < 2560; idx += 256) {
    int jj = idx / 10, d = idx % 10;
    zsm[jj * 12 + d] = z[(size_t)jbase * 10 + idx];
  }
  zsm[t * 12 + 10] = el[jbase + t];
  const float eri = er[i];
  const float mx = elmax[0];
  const float s0 = eri + mx;
  const float mi = fmaxf(s0, 0.2f * s0);  // leaky_relu monotone -> row max
  float num[10];
#pragma unroll
  for (int d = 0; d < 10; d++) num[d] = 0.f;
  float den = 0.f;
  __syncthreads();
  for (int jj = 0; jj < 256; jj++) {
    const float4 za = *(const float4*)(zsm + jj * 12);
    const float4 zb = *(const float4*)(zsm + jj * 12 + 4);
    const float2 zc = *(const float2*)(zsm + jj * 12 + 8);
    const float elj = zsm[jj * 12 + 10];
    const float s2 = eri + elj;
    const float lr = fmaxf(s2, 0.2f * s2);
    const float wgt = __expf(lr - mi);
    den += wgt;
    num[0] += wgt * za.x; num[1] += wgt * za.y; num[2] += wgt * za.z; num[3] += wgt * za.w;
    num[4] += wgt * zb.x; num[5] += wgt * zb.y; num[6] += wgt * zb.z; num[7] += wgt * zb.w;
    num[8] += wgt * zc.x; num[9] += wgt * zc.y;
  }
  float* pp = part + (size_t)split * 12 * 8192 + i;
#pragma unroll
  for (int d = 0; d < 10; d++) pp[d * 8192] = num[d];
  pp[10 * 8192] = den;
}

// ---------------- combine partials, divide, add bias
__global__ __launch_bounds__(256) void k_final(const float* __restrict__ part,
    const float* __restrict__ bg, float* __restrict__ out) {
  const int i = blockIdx.x * 256 + threadIdx.x;
  float num[10];
#pragma unroll
  for (int d = 0; d < 10; d++) num[d] = 0.f;
  float den = 0.f;
  for (int s = 0; s < 32; s++) {
    const float* pp = part + (size_t)s * 12 * 8192 + i;
#pragma unroll
    for (int d = 0; d < 10; d++) num[d] += pp[d * 8192];
    den += pp[10 * 8192];
  }
  const float inv = 1.f / den;
#pragma unroll
  for (int d = 0; d < 10; d++) out[(size_t)i * 10 + d] = num[d] * inv + bg[d];
}

extern "C" void kernel_launch(void* const* d_in, const int* in_sizes, int n_in,
                              void* d_out, int out_size, void* d_ws, size_t ws_size,
                              hipStream_t stream) {
  const float* x   = (const float*)d_in[0];
  const float* W1  = (const float*)d_in[1];
  const float* b1  = (const float*)d_in[2];
  const float* W2  = (const float*)d_in[3];
  const float* b2  = (const float*)d_in[4];
  const float* Wf1 = (const float*)d_in[5];
  const float* bf1 = (const float*)d_in[6];
  const float* Wf2 = (const float*)d_in[7];
  const float* bf2 = (const float*)d_in[8];
  const float* Wg  = (const float*)d_in[9];
  const float* al  = (const float*)d_in[10];
  const float* ar  = (const float*)d_in[11];
  const float* bg  = (const float*)d_in[12];
  float* out = (float*)d_out;

  float* ws = (float*)d_ws;
  _Float16* h1f = (_Float16*)ws;                        // 8192*1176 f16
  float* p = ws + (size_t)8192 * 588;                   // = 4,816,896 floats
  _Float16* h2f = (_Float16*)p;                         // 8192*416 f16
  p += (size_t)8192 * 208;
  float* z   = p; p += (size_t)8192 * 10;
  float* el  = p; p += 8192;
  float* er  = p; p += 8192;
  float* emx = p; p += 16;
  _Float16* w1f = (_Float16*)p; p += 26624;             // 128*416 f16
  _Float16* w2f = (_Float16*)p; p += 6144;              // 96*128 f16
  _Float16* wgf = (_Float16*)p; p += 768;               // 16*96 f16
  float* part = ws;                                     // aliases h1 (dead after conv2)

  k_prep<<<262, 256, 0, stream>>>(Wf1, Wf2, Wg, w1f, w2f, wgf);
  k_conv1<<<8192, 256, 0, stream>>>(x, W1, b1, h1f);
  k_conv2<<<1639, 256, 0, stream>>>(h1f, W2, b2, h2f);
  k_mlp<<<256, 256, 0, stream>>>(h2f, w1f, bf1, w2f, bf2, wgf, al, ar, z, el, er);
  k_elmax<<<1, 256, 0, stream>>>(el, emx);
  dim3 ag(32, 32);
  k_attn<<<ag, 256, 0, stream>>>(z, el, er, emx, part);
  k_final<<<32, 256, 0, stream>>>(part, bg, out);
}

// Round 4
// 313.105 us; speedup vs baseline: 1.4642x; 1.0547x over previous
//
#include <hip/hip_runtime.h>
#include <hip/hip_bf16.h>

typedef _Float16 half8 __attribute__((ext_vector_type(8)));
typedef __attribute__((aligned(4))) half8 half8_a4;  // 4B-aligned LDS load
typedef float floatx4 __attribute__((ext_vector_type(4)));

// ---------------- prep: f16 MLP weights + conv B-matrices
// w1f:[128][416] w2f:[96][128] wgf:[16][96]
// B1:[32][160]  n=co*4+cy*2+cx (co<6), k=ci*48+r*8+j (k<144 real)
// B2:[64][288]  n=co*4+cy*2+cx (co<16), k=ci*48+r*8+j
__global__ __launch_bounds__(256) void k_prep(const float* __restrict__ Wf1,
    const float* __restrict__ Wf2, const float* __restrict__ Wg,
    const float* __restrict__ W1, const float* __restrict__ W2,
    _Float16* __restrict__ w1f, _Float16* __restrict__ w2f,
    _Float16* __restrict__ wgf, _Float16* __restrict__ B1,
    _Float16* __restrict__ B2) {
  const int i = blockIdx.x * 256 + threadIdx.x;
  if (i < 53248) {
    const int n = i / 416, k = i - n * 416;
    w1f[i] = (_Float16)((n < 120 && k < 400) ? Wf1[n * 400 + k] : 0.f);
  } else if (i < 65536) {
    const int j = i - 53248;
    const int n = j >> 7, k = j & 127;
    w2f[j] = (_Float16)((n < 84 && k < 120) ? Wf2[n * 120 + k] : 0.f);
  } else if (i < 67072) {
    const int g = i - 65536;
    const int n = g / 96, k = g - n * 96;
    wgf[g] = (_Float16)((n < 10 && k < 84) ? Wg[n * 84 + k] : 0.f);
  } else if (i < 72192) {
    const int g = i - 67072;
    const int n = g / 160, k = g - n * 160;
    const int co = n >> 2, cy = (n >> 1) & 1, cx = n & 1;
    float v = 0.f;
    if (k < 144 && co < 6) {
      const int ci = k / 48, rj = k - ci * 48, r = rj >> 3, j = rj & 7;
      const int ky = r - cy, kx = j - cx;
      if (ky >= 0 && ky < 5 && kx >= 0 && kx < 5)
        v = W1[((co * 3 + ci) * 5 + ky) * 5 + kx];
    }
    B1[g] = (_Float16)v;
  } else if (i < 90624) {
    const int g = i - 72192;
    const int n = g / 288, k = g - n * 288;
    const int co = n >> 2, cy = (n >> 1) & 1, cx = n & 1;
    const int ci = k / 48, rj = k - ci * 48, r = rj >> 3, j = rj & 7;
    const int ky = r - cy, kx = j - cx;
    float v = 0.f;
    if (ky >= 0 && ky < 5 && kx >= 0 && kx < 5)
      v = W2[((co * 6 + ci) * 5 + ky) * 5 + kx];
    B2[g] = (_Float16)v;
  }
}

// ---------------- conv1 via MFMA: x[4 img] -> h1 f16 [img][6][196]
// M=784 (img,py,px), N=32 (co*4+corner, 24 real), K=160 (ci*48+r*8+j, 144 real)
// A[m][k] = x[ci][2py+r][2px+j] : 8 contiguous f16, even offset (4B aligned)
__global__ __launch_bounds__(256) void k_conv1(const float* __restrict__ x,
    const _Float16* __restrict__ B1, const float* __restrict__ b1,
    _Float16* __restrict__ h1) {
  __shared__ __align__(16) _Float16 A[4 * 3 * 32 * 36];  // rows padded 32->36 (zeros)
  const int t = threadIdx.x;
  const int n0 = blockIdx.x * 4;
  // zero row pads (cols 32..35)
  for (int rr = t; rr < 384; rr += 256) {
    *(float*)(A + rr * 36 + 32) = 0.f;
    *(float*)(A + rr * 36 + 34) = 0.f;
  }
  // stage 4 images fp32 -> f16
  const float4* x4 = (const float4*)(x + (size_t)n0 * 3072);
  for (int i = t; i < 3072; i += 256) {
    const float4 v = x4[i];
    const int img = i / 768, rem = i - img * 768;
    const int ci = rem >> 8, rem2 = rem & 255;
    const int y = rem2 >> 3, xq = (rem2 & 7) * 4;
    union { _Float16 h[4]; float2 f; } u;
    u.h[0] = (_Float16)v.x; u.h[1] = (_Float16)v.y;
    u.h[2] = (_Float16)v.z; u.h[3] = (_Float16)v.w;
    *(float2*)(A + (img * 3 + ci) * 1152 + y * 36 + xq) = u.f;
  }
  __syncthreads();
  const int w = t >> 6, lane = t & 63;
  const int l16 = lane & 15, q = lane >> 4;
  for (int nt = 0; nt < 2; nt++) {
    const int co = nt * 4 + (l16 >> 2);
    const float bias = (co < 6) ? b1[co] : 0.f;
    // B fragments for this n-tile (global, L2-hot)
    half8 bfr[5];
#pragma unroll
    for (int kc = 0; kc < 5; kc++)
      bfr[kc] = *(const half8*)(B1 + (size_t)(nt * 16 + l16) * 160 + kc * 32 + q * 8);
    const bool act = ((l16 & 3) == 0) && (co < 6);
    for (int mt = w; mt < 49; mt += 4) {
      const int m = mt * 16 + l16;
      const int img_l = m / 196, p = m - img_l * 196;
      const int py = p / 14, px = p - py * 14;
      half8 a[5];
#pragma unroll
      for (int kc = 0; kc < 5; kc++) {
        const int pidx = kc * 4 + q;
        const int ci = pidx / 6, r = pidx - ci * 6;
        const int off = (pidx < 18)
            ? (img_l * 3 + ci) * 1152 + (2 * py + r) * 36 + 2 * px : 0;
        a[kc] = *(const half8_a4*)(A + off);
      }
      floatx4 acc;
#pragma unroll
      for (int r = 0; r < 4; r++) acc[r] = 0.f;
#pragma unroll
      for (int kc = 0; kc < 5; kc++)
        acc = __builtin_amdgcn_mfma_f32_16x16x32_f16(a[kc], bfr[kc], acc, 0, 0, 0);
#pragma unroll
      for (int r = 0; r < 4; r++) {
        float v = acc[r];
        v = fmaxf(v, __shfl_xor(v, 1, 64));
        v = fmaxf(v, __shfl_xor(v, 2, 64));
        if (act) {
          const int mm = mt * 16 + q * 4 + r;
          const int im = mm / 196, pp = mm - im * 196;
          h1[(size_t)(n0 + im) * 1176 + co * 196 + pp] =
              (_Float16)fmaxf(v + bias, 0.f);
        }
      }
    }
  }
}

// ---------------- conv2 via MFMA: h1 f16 [8 img][6][196] -> h2 f16 [img][416]
// M=200->208 (img*25+p), N=64 (co*4+corner), K=288 (ci*48+r*8+j)
__global__ __launch_bounds__(256) void k_conv2(const _Float16* __restrict__ h1,
    const _Float16* __restrict__ B2, const float* __restrict__ b2,
    _Float16* __restrict__ h2) {
  __shared__ __align__(16) _Float16 A[8 * 6 * 14 * 16];  // rows padded 14->16
  const int t = threadIdx.x;
  const int n0 = blockIdx.x * 8;
  // stage 672 rows (8 img x 6 ci x 14 y): 7 dwords + zero pad dword
  for (int rr = t; rr < 672; rr += 256) {
    const int img = rr / 84, rem = rr - img * 84;
    const int ci = rem / 14, y = rem - ci * 14;
    const unsigned* src =
        (const unsigned*)(h1 + (size_t)(n0 + img) * 1176 + ci * 196 + y * 14);
    unsigned* dst = (unsigned*)(A + ((img * 6 + ci) * 14 + y) * 16);
#pragma unroll
    for (int k = 0; k < 7; k++) dst[k] = src[k];
    dst[7] = 0u;
  }
  // zero h2 k-pad [400..416)
  if (t < 128) {
    const int im = t >> 4;
    h2[(size_t)(n0 + im) * 416 + 400 + (t & 15)] = (_Float16)0.f;
  }
  __syncthreads();
  const int w = t >> 6, lane = t & 63;
  const int l16 = lane & 15, q = lane >> 4;
  for (int nt = 0; nt < 4; nt++) {
    const int co = nt * 4 + (l16 >> 2);
    const float bias = b2[co];
    half8 bfr[9];
#pragma unroll
    for (int kc = 0; kc < 9; kc++)
      bfr[kc] = *(const half8*)(B2 + (size_t)(nt * 16 + l16) * 288 + kc * 32 + q * 8);
    const bool act = ((l16 & 3) == 0);
    for (int mt = w; mt < 13; mt += 4) {
      const int m0 = mt * 16 + l16;
      const int m = m0 < 199 ? m0 : 199;
      const int img_l = m / 25, p = m - img_l * 25;
      const int py = p / 5, px = p - py * 5;
      half8 a[9];
#pragma unroll
      for (int kc = 0; kc < 9; kc++) {
        const int pidx = kc * 4 + q;
        const int ci = pidx / 6, r = pidx - ci * 6;
        const int off = ((img_l * 6 + ci) * 14 + (2 * py + r)) * 16 + 2 * px;
        a[kc] = *(const half8_a4*)(A + off);
      }
      floatx4 acc;
#pragma unroll
      for (int r = 0; r < 4; r++) acc[r] = 0.f;
#pragma unroll
      for (int kc = 0; kc < 9; kc++)
        acc = __builtin_amdgcn_mfma_f32_16x16x32_f16(a[kc], bfr[kc], acc, 0, 0, 0);
#pragma unroll
      for (int r = 0; r < 4; r++) {
        float v = acc[r];
        v = fmaxf(v, __shfl_xor(v, 1, 64));
        v = fmaxf(v, __shfl_xor(v, 2, 64));
        const int mm = mt * 16 + q * 4 + r;
        if (act && mm < 200) {
          const int im = mm / 25, pp = mm - im * 25;
          h2[(size_t)(n0 + im) * 416 + co * 25 + pp] =
              (_Float16)fmaxf(v + bias, 0.f);
        }
      }
    }
  }
}

// ---------------- fused MLP via f16 MFMA: fc1(relu) -> fc2(relu) -> z -> el/er
__global__ __launch_bounds__(256) void k_mlp(
    const _Float16* __restrict__ h2,   // [8192][416]
    const _Float16* __restrict__ w1,   // [128][416]
    const float* __restrict__ bf1,     // [120]
    const _Float16* __restrict__ w2,   // [96][128]
    const float* __restrict__ bf2,     // [84]
    const _Float16* __restrict__ wg,   // [16][96]
    const float* __restrict__ al, const float* __restrict__ ar,
    float* __restrict__ z, float* __restrict__ el, float* __restrict__ er) {
  __shared__ __align__(16) _Float16 h3s[32 * 136];
  __shared__ __align__(16) _Float16 h4s[32 * 104];
  __shared__ float zs[32 * 17];
  const int t = threadIdx.x;
  const int w = t >> 6, lane = t & 63;
  const int l16 = lane & 15, q = lane >> 4;
  const int row0 = blockIdx.x * 32;
  for (int i = t; i < 2176; i += 256) ((float*)h3s)[i] = 0.f;
  for (int i = t; i < 1664; i += 256) ((float*)h4s)[i] = 0.f;
  const int rt = w & 1, cg = w >> 1;
  const int am = row0 + rt * 16 + l16;
  floatx4 acc[4];
#pragma unroll
  for (int ct = 0; ct < 4; ct++)
#pragma unroll
    for (int r = 0; r < 4; r++) acc[ct][r] = 0.f;
  const half8* Ag = (const half8*)(h2 + (size_t)am * 416 + q * 8);
  for (int kc = 0; kc < 13; kc++) {
    half8 a = Ag[kc * 4];
#pragma unroll
    for (int ct = 0; ct < 4; ct++) {
      const int n = cg * 64 + ct * 16 + l16;
      half8 b = *(const half8*)(w1 + (size_t)n * 416 + kc * 32 + q * 8);
      acc[ct] = __builtin_amdgcn_mfma_f32_16x16x32_f16(a, b, acc[ct], 0, 0, 0);
    }
  }
  __syncthreads();
#pragma unroll
  for (int ct = 0; ct < 4; ct++) {
    const int n = cg * 64 + ct * 16 + l16;
    if (n < 120) {
      const float bias = bf1[n];
#pragma unroll
      for (int r = 0; r < 4; r++) {
        const int rr = rt * 16 + q * 4 + r;
        h3s[rr * 136 + n] = (_Float16)fmaxf(acc[ct][r] + bias, 0.f);
      }
    }
  }
  __syncthreads();
  const int cbase2 = (w >> 1) * 3;
  floatx4 acc2[3];
#pragma unroll
  for (int ct = 0; ct < 3; ct++)
#pragma unroll
    for (int r = 0; r < 4; r++) acc2[ct][r] = 0.f;
  const _Float16* A2 = h3s + (rt * 16 + l16) * 136 + q * 8;
  for (int kc = 0; kc < 4; kc++) {
    half8 a = *(const half8*)(A2 + kc * 32);
#pragma unroll
    for (int ct = 0; ct < 3; ct++) {
      const int n = (cbase2 + ct) * 16 + l16;
      half8 b = *(const half8*)(w2 + (size_t)n * 128 + kc * 32 + q * 8);
      acc2[ct] = __builtin_amdgcn_mfma_f32_16x16x32_f16(a, b, acc2[ct], 0, 0, 0);
    }
  }
  __syncthreads();
#pragma unroll
  for (int ct = 0; ct < 3; ct++) {
    const int n = (cbase2 + ct) * 16 + l16;
    if (n < 84) {
      const float bias = bf2[n];
#pragma unroll
      for (int r = 0; r < 4; r++) {
        const int rr = rt * 16 + q * 4 + r;
        h4s[rr * 104 + n] = (_Float16)fmaxf(acc2[ct][r] + bias, 0.f);
      }
    }
  }
  __syncthreads();
  if (w < 2) {
    floatx4 acc3;
#pragma unroll
    for (int r = 0; r < 4; r++) acc3[r] = 0.f;
    const _Float16* A3 = h4s + (w * 16 + l16) * 104 + q * 8;
    for (int kc = 0; kc < 3; kc++) {
      half8 a = *(const half8*)(A3 + kc * 32);
      half8 b = *(const half8*)(wg + (size_t)l16 * 96 + kc * 32 + q * 8);
      acc3 = __builtin_amdgcn_mfma_f32_16x16x32_f16(a, b, acc3, 0, 0, 0);
    }
#pragma unroll
    for (int r = 0; r < 4; r++) {
      const int rr = w * 16 + q * 4 + r;
      zs[rr * 17 + l16] = acc3[r];
      if (l16 < 10) z[(size_t)(row0 + rr) * 10 + l16] = acc3[r];
    }
  }
  __syncthreads();
  if (t < 32) {
    float e1 = 0.f, e2 = 0.f;
#pragma unroll
    for (int d = 0; d < 10; d++) {
      const float zv = zs[t * 17 + d];
      e1 += zv * al[d];
      e2 += zv * ar[d];
    }
    el[row0 + t] = e1;
    er[row0 + t] = e2;
  }
}

// ---------------- max over el
__global__ __launch_bounds__(256) void k_elmax(const float* __restrict__ el,
                                               float* __restrict__ out) {
  __shared__ float red[4];
  const int t = threadIdx.x;
  float m = -1e30f;
  for (int i = t; i < 8192; i += 256) m = fmaxf(m, el[i]);
#pragma unroll
  for (int off = 32; off > 0; off >>= 1) m = fmaxf(m, __shfl_down(m, off, 64));
  if ((t & 63) == 0) red[t >> 6] = m;
  __syncthreads();
  if (t == 0) out[0] = fmaxf(fmaxf(red[0], red[1]), fmaxf(red[2], red[3]));
}

// ---------------- attention partials: dst i per thread, 32 j-splits of 256
__global__ __launch_bounds__(256) void k_attn(const float* __restrict__ z,
    const float* __restrict__ el, const float* __restrict__ er,
    const float* __restrict__ elmax, float* __restrict__ part) {
  __shared__ __align__(16) float zsm[256 * 12];
  const int t = threadIdx.x;
  const int i = blockIdx.x * 256 + t;
  const int split = blockIdx.y;
  const int jbase = split * 256;
  for (int idx = t; idx < 2560; idx += 256) {
    int jj = idx / 10, d = idx - jj * 10;
    zsm[jj * 12 + d] = z[(size_t)jbase * 10 + idx];
  }
  zsm[t * 12 + 10] = el[jbase + t];
  const float eri = er[i];
  const float mx = elmax[0];
  const float s0 = eri + mx;
  const float mi = fmaxf(s0, 0.2f * s0);
  float num[10];
#pragma unroll
  for (int d = 0; d < 10; d++) num[d] = 0.f;
  float den = 0.f;
  __syncthreads();
  for (int jj = 0; jj < 256; jj++) {
    const float4 za = *(const float4*)(zsm + jj * 12);
    const float4 zb = *(const float4*)(zsm + jj * 12 + 4);
    const float2 zc = *(const float2*)(zsm + jj * 12 + 8);
    const float elj = zsm[jj * 12 + 10];
    const float s2 = eri + elj;
    const float lr = fmaxf(s2, 0.2f * s2);
    const float wgt = __expf(lr - mi);
    den += wgt;
    num[0] += wgt * za.x; num[1] += wgt * za.y; num[2] += wgt * za.z; num[3] += wgt * za.w;
    num[4] += wgt * zb.x; num[5] += wgt * zb.y; num[6] += wgt * zb.z; num[7] += wgt * zb.w;
    num[8] += wgt * zc.x; num[9] += wgt * zc.y;
  }
  float* pp = part + (size_t)split * 12 * 8192 + i;
#pragma unroll
  for (int d = 0; d < 10; d++) pp[d * 8192] = num[d];
  pp[10 * 8192] = den;
}

// ---------------- combine partials, divide, add bias
__global__ __launch_bounds__(256) void k_final(const float* __restrict__ part,
    const float* __restrict__ bg, float* __restrict__ out) {
  const int i = blockIdx.x * 256 + threadIdx.x;
  float num[10];
#pragma unroll
  for (int d = 0; d < 10; d++) num[d] = 0.f;
  float den = 0.f;
  for (int s = 0; s < 32; s++) {
    const float* pp = part + (size_t)s * 12 * 8192 + i;
#pragma unroll
    for (int d = 0; d < 10; d++) num[d] += pp[d * 8192];
    den += pp[10 * 8192];
  }
  const float inv = 1.f / den;
#pragma unroll
  for (int d = 0; d < 10; d++) out[(size_t)i * 10 + d] = num[d] * inv + bg[d];
}

extern "C" void kernel_launch(void* const* d_in, const int* in_sizes, int n_in,
                              void* d_out, int out_size, void* d_ws, size_t ws_size,
                              hipStream_t stream) {
  const float* x   = (const float*)d_in[0];
  const float* W1  = (const float*)d_in[1];
  const float* b1  = (const float*)d_in[2];
  const float* W2  = (const float*)d_in[3];
  const float* b2  = (const float*)d_in[4];
  const float* Wf1 = (const float*)d_in[5];
  const float* bf1 = (const float*)d_in[6];
  const float* Wf2 = (const float*)d_in[7];
  const float* bf2 = (const float*)d_in[8];
  const float* Wg  = (const float*)d_in[9];
  const float* al  = (const float*)d_in[10];
  const float* ar  = (const float*)d_in[11];
  const float* bg  = (const float*)d_in[12];
  float* out = (float*)d_out;

  float* ws = (float*)d_ws;
  _Float16* h1f = (_Float16*)ws;                        // 8192*1176 f16
  float* p = ws + (size_t)8192 * 588;
  _Float16* h2f = (_Float16*)p;                         // 8192*416 f16
  p += (size_t)8192 * 208;
  float* z   = p; p += (size_t)8192 * 10;
  float* el  = p; p += 8192;
  float* er  = p; p += 8192;
  float* emx = p; p += 16;
  _Float16* w1f = (_Float16*)p; p += 26624;             // 128*416 f16
  _Float16* w2f = (_Float16*)p; p += 6144;              // 96*128 f16
  _Float16* wgf = (_Float16*)p; p += 768;               // 16*96 f16
  _Float16* B1g = (_Float16*)p; p += 2560;              // 32*160 f16
  _Float16* B2g = (_Float16*)p; p += 9216;              // 64*288 f16
  float* part = ws;                                     // aliases h1 (dead after conv2)

  k_prep<<<354, 256, 0, stream>>>(Wf1, Wf2, Wg, W1, W2, w1f, w2f, wgf, B1g, B2g);
  k_conv1<<<2048, 256, 0, stream>>>(x, B1g, b1, h1f);
  k_conv2<<<1024, 256, 0, stream>>>(h1f, B2g, b2, h2f);
  k_mlp<<<256, 256, 0, stream>>>(h2f, w1f, bf1, w2f, bf2, wgf, al, ar, z, el, er);
  k_elmax<<<1, 256, 0, stream>>>(el, emx);
  dim3 ag(32, 32);
  k_attn<<<ag, 256, 0, stream>>>(z, el, er, emx, part);
  k_final<<<32, 256, 0, stream>>>(part, bg, out);
}

// Round 5
// 295.717 us; speedup vs baseline: 1.5503x; 1.0588x over previous
//
#include <hip/hip_runtime.h>
#include <hip/hip_bf16.h>

typedef _Float16 half8 __attribute__((ext_vector_type(8)));
typedef __attribute__((aligned(8))) half8 half8_a8;  // -> 2x ds_read_b64
typedef float floatx4 __attribute__((ext_vector_type(4)));

// ---------------- prep: f16 MLP weights + conv B-matrices
// w1f:[128][416] w2f:[96][128] wgf:[16][96]
// B1:[32][160]  n=co*4+cy*2+cx (co<6), k=(ci*6+r)*8+j (k<144 real; r=0..5)
// B2M:[16][256] n=co,           k=(ci*5+r)*8+j (k<240 real; r=0..4, j<5 real)
__global__ __launch_bounds__(256) void k_prep(const float* __restrict__ Wf1,
    const float* __restrict__ Wf2, const float* __restrict__ Wg,
    const float* __restrict__ W1, const float* __restrict__ W2,
    _Float16* __restrict__ w1f, _Float16* __restrict__ w2f,
    _Float16* __restrict__ wgf, _Float16* __restrict__ B1,
    _Float16* __restrict__ B2M) {
  const int i = blockIdx.x * 256 + threadIdx.x;
  if (i < 53248) {
    const int n = i / 416, k = i - n * 416;
    w1f[i] = (_Float16)((n < 120 && k < 400) ? Wf1[n * 400 + k] : 0.f);
  } else if (i < 65536) {
    const int j = i - 53248;
    const int n = j >> 7, k = j & 127;
    w2f[j] = (_Float16)((n < 84 && k < 120) ? Wf2[n * 120 + k] : 0.f);
  } else if (i < 67072) {
    const int g = i - 65536;
    const int n = g / 96, k = g - n * 96;
    wgf[g] = (_Float16)((n < 10 && k < 84) ? Wg[n * 84 + k] : 0.f);
  } else if (i < 72192) {
    const int g = i - 67072;
    const int n = g / 160, k = g - n * 160;
    const int co = n >> 2, cy = (n >> 1) & 1, cx = n & 1;
    float v = 0.f;
    if (k < 144 && co < 6) {
      const int ci = k / 48, rj = k - ci * 48, r = rj >> 3, j = rj & 7;
      const int ky = r - cy, kx = j - cx;
      if (ky >= 0 && ky < 5 && kx >= 0 && kx < 5)
        v = W1[((co * 3 + ci) * 5 + ky) * 5 + kx];
    }
    B1[g] = (_Float16)v;
  } else if (i < 76288) {
    const int g = i - 72192;
    const int n = g >> 8, k = g & 255;
    float v = 0.f;
    if (k < 240) {
      const int ci = k / 40, rem = k - ci * 40, r = rem >> 3, j = rem & 7;
      if (j < 5) v = W2[((n * 6 + ci) * 5 + r) * 5 + j];
    }
    B2M[g] = (_Float16)v;
  }
}

// ---------------- conv1 via MFMA, corner-in-N, dual-shift LDS copies
// 2 img/block. M=392, N=32(24 real), K=160(144 real).
// LDS chunk per (img,ci) = 5184B: copy0 rows y*80B (32 halfs data),
// copy1 at +2592 (copy1[c]=orig[c+2]). Fragment start byte 4px(-4) -> 8B aligned.
__global__ __launch_bounds__(256) void k_conv1(const float* __restrict__ x,
    const _Float16* __restrict__ B1, const float* __restrict__ b1,
    _Float16* __restrict__ h1) {
  __shared__ __align__(16) char sm[31104];
  const int t = threadIdx.x;
  const int n0 = blockIdx.x * 2;
  // stage: 1536 float4 (2 img x 3 ci x 32 y x 8 quads)
  const float4* x4 = (const float4*)(x + (size_t)n0 * 3072);
  for (int i = t; i < 1536; i += 256) {
    const float4 v = x4[i];
    const int img = i / 768, rem = i - img * 768;
    const int ci = rem >> 8, rem2 = rem & 255;
    const int y = rem2 >> 3, c = rem2 & 7;
    union { _Float16 h[2]; unsigned u; } p01, p23;
    p01.h[0] = (_Float16)v.x; p01.h[1] = (_Float16)v.y;
    p23.h[0] = (_Float16)v.z; p23.h[1] = (_Float16)v.w;
    char* ch = sm + (img * 3 + ci) * 5184 + y * 80;
    *(uint2*)(ch + 8 * c) = make_uint2(p01.u, p23.u);      // copy0
    *(unsigned*)(ch + 2592 + 8 * c - 4) = p01.u;           // copy1 (c=0 -> gap)
    *(unsigned*)(ch + 2592 + 8 * c) = p23.u;
  }
  // copy1 zero tail (cols 30,31 = orig 32,33)
  if (t < 192) {
    const int img = t / 96, r2 = t - img * 96, ci = r2 >> 5, y = r2 & 31;
    *(unsigned*)(sm + (img * 3 + ci) * 5184 + 2592 + y * 80 + 60) = 0u;
  }
  __syncthreads();
  const int w = t >> 6, lane = t & 63;
  const int l16 = lane & 15, q = lane >> 4;
  // per-lane k-chunk offsets: pidx = kc*4+q -> (ci, r)
  int C1[5];
#pragma unroll
  for (int kc = 0; kc < 5; kc++) {
    const int pidx = kc * 4 + q;
    C1[kc] = (pidx < 18) ? (pidx / 6) * 5184 + (pidx % 6) * 80 : 0;
  }
  // B fragments (global, L2-hot), both n-tiles
  half8 bfr[2][5];
#pragma unroll
  for (int nt = 0; nt < 2; nt++)
#pragma unroll
    for (int kc = 0; kc < 5; kc++)
      bfr[nt][kc] =
          *(const half8*)(B1 + (size_t)(nt * 16 + l16) * 160 + kc * 32 + q * 8);
  const int co0 = l16 >> 2, co1 = 4 + (l16 >> 2);
  const float bias0 = b1[co0 < 6 ? co0 : 0];
  const float bias1 = (co1 < 6) ? b1[co1] : 0.f;
  const bool lact = (l16 & 3) == 0;
  for (int mt = w; mt < 25; mt += 4) {
    const int m = min(mt * 16 + l16, 391);
    const int img = m / 196, p = m - img * 196;
    const int py = p / 14, px = p - py * 14;
    const int colOff = 4 * px + ((px & 1) ? 2588 : 0);
    const char* base = sm + img * 15552 + py * 160 + colOff;
    half8 a[5];
#pragma unroll
    for (int kc = 0; kc < 5; kc++) a[kc] = *(const half8_a8*)(base + C1[kc]);
#pragma unroll
    for (int nt = 0; nt < 2; nt++) {
      floatx4 acc;
#pragma unroll
      for (int r = 0; r < 4; r++) acc[r] = 0.f;
#pragma unroll
      for (int kc = 0; kc < 5; kc++)
        acc = __builtin_amdgcn_mfma_f32_16x16x32_f16(a[kc], bfr[nt][kc], acc, 0, 0, 0);
      const int co = nt ? co1 : co0;
      const float bias = nt ? bias1 : bias0;
      const bool act = lact && co < 6;
#pragma unroll
      for (int r = 0; r < 4; r++) {
        float v = acc[r];
        v = fmaxf(v, __shfl_xor(v, 1, 64));
        v = fmaxf(v, __shfl_xor(v, 2, 64));
        const int mm = mt * 16 + q * 4 + r;
        if (act && mm < 392) {
          const int im = mm / 196, pp = mm - im * 196;
          h1[(size_t)(n0 + im) * 1176 + co * 196 + pp] =
              (_Float16)fmaxf(v + bias, 0.f);
        }
      }
    }
  }
}

// ---------------- conv2 via MFMA, corner-in-M, 4 shift copies
// 2 img/block. m = pos*4 + (cy*2+cx), pos = img*25+py*5+px. N=16 (co), K=256.
// LDS chunk per (img,ci) = 1856B: copy_s at s*464, rows 32B (16 halfs).
// copy_s[c] = orig[c+s]; fragment start (2px+cx) - s -> 8B aligned.
// Pooling = max over the 4 accumulator regs (rows m%4) -> 1 store/lane.
__global__ __launch_bounds__(256) void k_conv2(const _Float16* __restrict__ h1,
    const _Float16* __restrict__ B2M, const float* __restrict__ b2,
    _Float16* __restrict__ h2) {
  __shared__ __align__(16) char sm[22272];
  const int t = threadIdx.x;
  const int n0 = blockIdx.x * 2;
  // stage: 168 rows (2 img x 6 ci x 14 y), build 4 shifted copies
  if (t < 168) {
    const int img = t / 84, rem = t - img * 84;
    const int ci = rem / 14, y = rem - ci * 14;
    const unsigned* src =
        (const unsigned*)(h1 + (size_t)(n0 + img) * 1176 + ci * 196 + y * 14);
    unsigned u[10];
#pragma unroll
    for (int k = 0; k < 7; k++) u[k] = src[k];
    u[7] = 0u; u[8] = 0u; u[9] = 0u;
    char* base = sm + img * 11136 + ci * 1856 + y * 32;
#pragma unroll
    for (int ww = 0; ww < 8; ww++) {
      *(unsigned*)(base + 4 * ww) = u[ww];                                  // s=0
      *(unsigned*)(base + 464 + 4 * ww) = (u[ww] >> 16) | (u[ww + 1] << 16); // s=1
      *(unsigned*)(base + 928 + 4 * ww) = u[ww + 1];                         // s=2
      *(unsigned*)(base + 1392 + 4 * ww) = (u[ww + 1] >> 16) | (u[ww + 2] << 16); // s=3
    }
  }
  // zero h2 k-pad [400..416)
  if (t < 32) {
    const int im = t >> 4;
    h2[(size_t)(n0 + im) * 416 + 400 + (t & 15)] = (_Float16)0.f;
  }
  __syncthreads();
  const int w = t >> 6, lane = t & 63;
  const int l16 = lane & 15, q = lane >> 4;
  int C2[8];
#pragma unroll
  for (int kc = 0; kc < 8; kc++) {
    const int pidx = kc * 4 + q;
    C2[kc] = (pidx < 30) ? (pidx / 5) * 1856 + (pidx % 5) * 32 : 0;
  }
  half8 bfr[8];
#pragma unroll
  for (int kc = 0; kc < 8; kc++)
    bfr[kc] = *(const half8*)(B2M + (size_t)l16 * 256 + kc * 32 + q * 8);
  const float bias = b2[l16];
  for (int mt = w; mt < 13; mt += 4) {
    const int m = min(mt * 16 + l16, 199);
    const int pos = m >> 2, cy = (m >> 1) & 1, cx = m & 1;
    const int img = pos / 25, p = pos - img * 25;
    const int py = p / 5, px = p - py * 5;
    const int h = 2 * px + cx, s = h & 3;
    const char* base =
        sm + img * 11136 + s * 464 + (2 * py + cy) * 32 + (h - s) * 2;
    half8 a[8];
#pragma unroll
    for (int kc = 0; kc < 8; kc++) a[kc] = *(const half8_a8*)(base + C2[kc]);
    floatx4 acc;
#pragma unroll
    for (int r = 0; r < 4; r++) acc[r] = 0.f;
#pragma unroll
    for (int kc = 0; kc < 8; kc++)
      acc = __builtin_amdgcn_mfma_f32_16x16x32_f16(a[kc], bfr[kc], acc, 0, 0, 0);
    const float v = fmaxf(fmaxf(acc[0], acc[1]), fmaxf(acc[2], acc[3]));
    const int posL = mt * 4 + q;
    if (posL < 50) {
      const int im = posL / 25, pp = posL - im * 25;
      h2[(size_t)(n0 + im) * 416 + l16 * 25 + pp] =
          (_Float16)fmaxf(v + bias, 0.f);
    }
  }
}

// ---------------- fused MLP via f16 MFMA: fc1(relu) -> fc2(relu) -> z -> el/er
__global__ __launch_bounds__(256) void k_mlp(
    const _Float16* __restrict__ h2,   // [8192][416]
    const _Float16* __restrict__ w1,   // [128][416]
    const float* __restrict__ bf1,     // [120]
    const _Float16* __restrict__ w2,   // [96][128]
    const float* __restrict__ bf2,     // [84]
    const _Float16* __restrict__ wg,   // [16][96]
    const float* __restrict__ al, const float* __restrict__ ar,
    float* __restrict__ z, float* __restrict__ el, float* __restrict__ er) {
  __shared__ __align__(16) _Float16 h3s[32 * 136];
  __shared__ __align__(16) _Float16 h4s[32 * 104];
  __shared__ float zs[32 * 17];
  const int t = threadIdx.x;
  const int w = t >> 6, lane = t & 63;
  const int l16 = lane & 15, q = lane >> 4;
  const int row0 = blockIdx.x * 32;
  for (int i = t; i < 2176; i += 256) ((float*)h3s)[i] = 0.f;
  for (int i = t; i < 1664; i += 256) ((float*)h4s)[i] = 0.f;
  const int rt = w & 1, cg = w >> 1;
  const int am = row0 + rt * 16 + l16;
  floatx4 acc[4];
#pragma unroll
  for (int ct = 0; ct < 4; ct++)
#pragma unroll
    for (int r = 0; r < 4; r++) acc[ct][r] = 0.f;
  const half8* Ag = (const half8*)(h2 + (size_t)am * 416 + q * 8);
  for (int kc = 0; kc < 13; kc++) {
    half8 a = Ag[kc * 4];
#pragma unroll
    for (int ct = 0; ct < 4; ct++) {
      const int n = cg * 64 + ct * 16 + l16;
      half8 b = *(const half8*)(w1 + (size_t)n * 416 + kc * 32 + q * 8);
      acc[ct] = __builtin_amdgcn_mfma_f32_16x16x32_f16(a, b, acc[ct], 0, 0, 0);
    }
  }
  __syncthreads();
#pragma unroll
  for (int ct = 0; ct < 4; ct++) {
    const int n = cg * 64 + ct * 16 + l16;
    if (n < 120) {
      const float bias = bf1[n];
#pragma unroll
      for (int r = 0; r < 4; r++) {
        const int rr = rt * 16 + q * 4 + r;
        h3s[rr * 136 + n] = (_Float16)fmaxf(acc[ct][r] + bias, 0.f);
      }
    }
  }
  __syncthreads();
  const int cbase2 = (w >> 1) * 3;
  floatx4 acc2[3];
#pragma unroll
  for (int ct = 0; ct < 3; ct++)
#pragma unroll
    for (int r = 0; r < 4; r++) acc2[ct][r] = 0.f;
  const _Float16* A2 = h3s + (rt * 16 + l16) * 136 + q * 8;
  for (int kc = 0; kc < 4; kc++) {
    half8 a = *(const half8*)(A2 + kc * 32);
#pragma unroll
    for (int ct = 0; ct < 3; ct++) {
      const int n = (cbase2 + ct) * 16 + l16;
      half8 b = *(const half8*)(w2 + (size_t)n * 128 + kc * 32 + q * 8);
      acc2[ct] = __builtin_amdgcn_mfma_f32_16x16x32_f16(a, b, acc2[ct], 0, 0, 0);
    }
  }
  __syncthreads();
#pragma unroll
  for (int ct = 0; ct < 3; ct++) {
    const int n = (cbase2 + ct) * 16 + l16;
    if (n < 84) {
      const float bias = bf2[n];
#pragma unroll
      for (int r = 0; r < 4; r++) {
        const int rr = rt * 16 + q * 4 + r;
        h4s[rr * 104 + n] = (_Float16)fmaxf(acc2[ct][r] + bias, 0.f);
      }
    }
  }
  __syncthreads();
  if (w < 2) {
    floatx4 acc3;
#pragma unroll
    for (int r = 0; r < 4; r++) acc3[r] = 0.f;
    const _Float16* A3 = h4s + (w * 16 + l16) * 104 + q * 8;
    for (int kc = 0; kc < 3; kc++) {
      half8 a = *(const half8*)(A3 + kc * 32);
      half8 b = *(const half8*)(wg + (size_t)l16 * 96 + kc * 32 + q * 8);
      acc3 = __builtin_amdgcn_mfma_f32_16x16x32_f16(a, b, acc3, 0, 0, 0);
    }
#pragma unroll
    for (int r = 0; r < 4; r++) {
      const int rr = w * 16 + q * 4 + r;
      zs[rr * 17 + l16] = acc3[r];
      if (l16 < 10) z[(size_t)(row0 + rr) * 10 + l16] = acc3[r];
    }
  }
  __syncthreads();
  if (t < 32) {
    float e1 = 0.f, e2 = 0.f;
#pragma unroll
    for (int d = 0; d < 10; d++) {
      const float zv = zs[t * 17 + d];
      e1 += zv * al[d];
      e2 += zv * ar[d];
    }
    el[row0 + t] = e1;
    er[row0 + t] = e2;
  }
}

// ---------------- max over el
__global__ __launch_bounds__(256) void k_elmax(const float* __restrict__ el,
                                               float* __restrict__ out) {
  __shared__ float red[4];
  const int t = threadIdx.x;
  float m = -1e30f;
  for (int i = t; i < 8192; i += 256) m = fmaxf(m, el[i]);
#pragma unroll
  for (int off = 32; off > 0; off >>= 1) m = fmaxf(m, __shfl_down(m, off, 64));
  if ((t & 63) == 0) red[t >> 6] = m;
  __syncthreads();
  if (t == 0) out[0] = fmaxf(fmaxf(red[0], red[1]), fmaxf(red[2], red[3]));
}

// ---------------- attention partials: dst i per thread, 32 j-splits of 256
__global__ __launch_bounds__(256) void k_attn(const float* __restrict__ z,
    const float* __restrict__ el, const float* __restrict__ er,
    const float* __restrict__ elmax, float* __restrict__ part) {
  __shared__ __align__(16) float zsm[256 * 12];
  const int t = threadIdx.x;
  const int i = blockIdx.x * 256 + t;
  const int split = blockIdx.y;
  const int jbase = split * 256;
  for (int idx = t; idx < 2560; idx += 256) {
    int jj = idx / 10, d = idx - jj * 10;
    zsm[jj * 12 + d] = z[(size_t)jbase * 10 + idx];
  }
  zsm[t * 12 + 10] = el[jbase + t];
  const float eri = er[i];
  const float mx = elmax[0];
  const float s0 = eri + mx;
  const float mi = fmaxf(s0, 0.2f * s0);
  float num[10];
#pragma unroll
  for (int d = 0; d < 10; d++) num[d] = 0.f;
  float den = 0.f;
  __syncthreads();
  for (int jj = 0; jj < 256; jj++) {
    const float4 za = *(const float4*)(zsm + jj * 12);
    const float4 zb = *(const float4*)(zsm + jj * 12 + 4);
    const float2 zc = *(const float2*)(zsm + jj * 12 + 8);
    const float elj = zsm[jj * 12 + 10];
    const float s2 = eri + elj;
    const float lr = fmaxf(s2, 0.2f * s2);
    const float wgt = __expf(lr - mi);
    den += wgt;
    num[0] += wgt * za.x; num[1] += wgt * za.y; num[2] += wgt * za.z; num[3] += wgt * za.w;
    num[4] += wgt * zb.x; num[5] += wgt * zb.y; num[6] += wgt * zb.z; num[7] += wgt * zb.w;
    num[8] += wgt * zc.x; num[9] += wgt * zc.y;
  }
  float* pp = part + (size_t)split * 12 * 8192 + i;
#pragma unroll
  for (int d = 0; d < 10; d++) pp[d * 8192] = num[d];
  pp[10 * 8192] = den;
}

// ---------------- combine partials, divide, add bias
__global__ __launch_bounds__(256) void k_final(const float* __restrict__ part,
    const float* __restrict__ bg, float* __restrict__ out) {
  const int i = blockIdx.x * 256 + threadIdx.x;
  float num[10];
#pragma unroll
  for (int d = 0; d < 10; d++) num[d] = 0.f;
  float den = 0.f;
  for (int s = 0; s < 32; s++) {
    const float* pp = part + (size_t)s * 12 * 8192 + i;
#pragma unroll
    for (int d = 0; d < 10; d++) num[d] += pp[d * 8192];
    den += pp[10 * 8192];
  }
  const float inv = 1.f / den;
#pragma unroll
  for (int d = 0; d < 10; d++) out[(size_t)i * 10 + d] = num[d] * inv + bg[d];
}

extern "C" void kernel_launch(void* const* d_in, const int* in_sizes, int n_in,
                              void* d_out, int out_size, void* d_ws, size_t ws_size,
                              hipStream_t stream) {
  const float* x   = (const float*)d_in[0];
  const float* W1  = (const float*)d_in[1];
  const float* b1  = (const float*)d_in[2];
  const float* W2  = (const float*)d_in[3];
  const float* b2  = (const float*)d_in[4];
  const float* Wf1 = (const float*)d_in[5];
  const float* bf1 = (const float*)d_in[6];
  const float* Wf2 = (const float*)d_in[7];
  const float* bf2 = (const float*)d_in[8];
  const float* Wg  = (const float*)d_in[9];
  const float* al  = (const float*)d_in[10];
  const float* ar  = (const float*)d_in[11];
  const float* bg  = (const float*)d_in[12];
  float* out = (float*)d_out;

  float* ws = (float*)d_ws;
  _Float16* h1f = (_Float16*)ws;                        // 8192*1176 f16
  float* p = ws + (size_t)8192 * 588;
  _Float16* h2f = (_Float16*)p;                         // 8192*416 f16
  p += (size_t)8192 * 208;
  float* z   = p; p += (size_t)8192 * 10;
  float* el  = p; p += 8192;
  float* er  = p; p += 8192;
  float* emx = p; p += 16;
  _Float16* w1f = (_Float16*)p; p += 26624;             // 128*416 f16
  _Float16* w2f = (_Float16*)p; p += 6144;              // 96*128 f16
  _Float16* wgf = (_Float16*)p; p += 768;               // 16*96 f16
  _Float16* B1g = (_Float16*)p; p += 2560;              // 32*160 f16
  _Float16* B2g = (_Float16*)p; p += 2048;              // 16*256 f16
  float* part = ws;                                     // aliases h1 (dead after conv2)

  k_prep<<<298, 256, 0, stream>>>(Wf1, Wf2, Wg, W1, W2, w1f, w2f, wgf, B1g, B2g);
  k_conv1<<<4096, 256, 0, stream>>>(x, B1g, b1, h1f);
  k_conv2<<<4096, 256, 0, stream>>>(h1f, B2g, b2, h2f);
  k_mlp<<<256, 256, 0, stream>>>(h2f, w1f, bf1, w2f, bf2, wgf, al, ar, z, el, er);
  k_elmax<<<1, 256, 0, stream>>>(el, emx);
  dim3 ag(32, 32);
  k_attn<<<ag, 256, 0, stream>>>(z, el, er, emx, part);
  k_final<<<32, 256, 0, stream>>>(part, bg, out);
}

// Round 6
// 286.600 us; speedup vs baseline: 1.5996x; 1.0318x over previous
//
#include <hip/hip_runtime.h>
#include <hip/hip_bf16.h>

typedef _Float16 half8 __attribute__((ext_vector_type(8)));
typedef __attribute__((aligned(8))) half8 half8_a8;  // -> 2x ds_read_b64
typedef float floatx4 __attribute__((ext_vector_type(4)));

// DPP cross-lane max within quads (pooling over corner = lane&3), no DS pipe
__device__ __forceinline__ float pool4_dpp(float v) {
  int s1 = __builtin_amdgcn_update_dpp(0, __float_as_int(v), 0xB1, 0xF, 0xF, true); // xor1
  float v1 = fmaxf(v, __int_as_float(s1));
  int s2 = __builtin_amdgcn_update_dpp(0, __float_as_int(v1), 0x4E, 0xF, 0xF, true); // xor2
  return fmaxf(v1, __int_as_float(s2));
}

// ---------------- prep: f16 MLP weights + conv B-matrices
// w1f:[128][416] w2f:[96][128] wgf:[16][96]
// B1:[32][192]  n=co*4+cy*2+cx (co<6), k=pidx*8+j, pidx=r*4+ci (r<6,ci<3)
// B2M:[16][256] n=co, k=(ci*5+r)*8+j (j<5 real)
__global__ __launch_bounds__(256) void k_prep(const float* __restrict__ Wf1,
    const float* __restrict__ Wf2, const float* __restrict__ Wg,
    const float* __restrict__ W1, const float* __restrict__ W2,
    _Float16* __restrict__ w1f, _Float16* __restrict__ w2f,
    _Float16* __restrict__ wgf, _Float16* __restrict__ B1,
    _Float16* __restrict__ B2M) {
  const int i = blockIdx.x * 256 + threadIdx.x;
  if (i < 53248) {
    const int n = i / 416, k = i - n * 416;
    w1f[i] = (_Float16)((n < 120 && k < 400) ? Wf1[n * 400 + k] : 0.f);
  } else if (i < 65536) {
    const int j = i - 53248;
    const int n = j >> 7, k = j & 127;
    w2f[j] = (_Float16)((n < 84 && k < 120) ? Wf2[n * 120 + k] : 0.f);
  } else if (i < 67072) {
    const int g = i - 65536;
    const int n = g / 96, k = g - n * 96;
    wgf[g] = (_Float16)((n < 10 && k < 84) ? Wg[n * 84 + k] : 0.f);
  } else if (i < 73216) {
    const int g = i - 67072;
    const int n = g / 192, k = g - n * 192;
    const int co = n >> 2, cy = (n >> 1) & 1, cx = n & 1;
    const int pidx = k >> 3, j = k & 7;
    const int r = pidx >> 2, ci = pidx & 3;
    float v = 0.f;
    if (co < 6 && ci < 3) {
      const int ky = r - cy, kx = j - cx;
      if (ky >= 0 && ky < 5 && kx >= 0 && kx < 5)
        v = W1[((co * 3 + ci) * 5 + ky) * 5 + kx];
    }
    B1[g] = (_Float16)v;
  } else if (i < 77312) {
    const int g = i - 73216;
    const int n = g >> 8, k = g & 255;
    float v = 0.f;
    if (k < 240) {
      const int ci = k / 40, rem = k - ci * 40, r = rem >> 3, j = rem & 7;
      if (j < 5) v = W2[((n * 6 + ci) * 5 + r) * 5 + j];
    }
    B2M[g] = (_Float16)v;
  }
}

// ---------------- conv1 via MFMA, corner-in-N, rolling py-window, DPP pooling
// 2 img/block. Per (img, py) m-tile: m = px (l16), n = co*4+corner (24 of 32),
// K = 192 (kc=r 0..5, q=ci). LDS per (img,ci) plane = 5184B: copy0 at 0
// (rows 80B, 8B-aligned), copy1 = identical copy at +2596 (base==4 mod 8) so
// odd px fragments are 8B-aligned. Wave w: img=w>>1, py half = w&1.
__global__ __launch_bounds__(256) void k_conv1(const float* __restrict__ x,
    const _Float16* __restrict__ B1, const float* __restrict__ b1,
    _Float16* __restrict__ h1) {
  __shared__ __align__(16) char sm[31104];
  const int t = threadIdx.x;
  const int n0 = blockIdx.x * 2;
  const float4* x4 = (const float4*)(x + (size_t)n0 * 3072);
  for (int i = t; i < 1536; i += 256) {
    const float4 v = x4[i];
    const int img = i / 768, rem = i - img * 768;
    const int ci = rem >> 8, rem2 = rem & 255;
    const int y = rem2 >> 3, c = rem2 & 7;
    union { _Float16 h[2]; unsigned u; } p01, p23;
    p01.h[0] = (_Float16)v.x; p01.h[1] = (_Float16)v.y;
    p23.h[0] = (_Float16)v.z; p23.h[1] = (_Float16)v.w;
    char* row = sm + (img * 3 + ci) * 5184 + y * 80;
    *(uint2*)(row + 8 * c) = make_uint2(p01.u, p23.u);
    *(unsigned*)(row + 2596 + 8 * c) = p01.u;
    *(unsigned*)(row + 2600 + 8 * c) = p23.u;
  }
  // zero copy1 halfs 32,33 per row (read by px=13 j-pad; B=0 but avoid NaN*0)
  if (t < 192) {
    const int img = t / 96, r2 = t - img * 96, ci = r2 >> 5, y = r2 & 31;
    *(unsigned*)(sm + (img * 3 + ci) * 5184 + 2596 + y * 80 + 64) = 0u;
  }
  __syncthreads();
  const int w4 = t >> 6, lane = t & 63;
  const int l16 = lane & 15, q = lane >> 4;
  const int px = l16;
  const int colOff = (px & 1) ? (2596 + 4 * px) : (4 * px);
  const char* base = sm + ((q == 3) ? 0 : q * 5184) + colOff;
  half8 bfr[2][6];
#pragma unroll
  for (int nt = 0; nt < 2; nt++)
#pragma unroll
    for (int kc = 0; kc < 6; kc++)
      bfr[nt][kc] =
          *(const half8*)(B1 + (size_t)(nt * 16 + l16) * 192 + kc * 32 + q * 8);
  const int co_n = l16 >> 2;        // nt0 output channel (0..3)
  const int co1 = 4 + co_n;         // nt1 (4..7; 6,7 dead)
  const float bias0 = b1[co_n];
  const float bias1 = (co1 < 6) ? b1[co1] : 0.f;
  const int img_w = w4 >> 1, pyh = w4 & 1;
  const int py0 = pyh * 7;
  const char* ibase = base + img_w * 15552;
  half8 a[6];
#pragma unroll
  for (int r = 0; r < 6; r++)
    a[r] = *(const half8_a8*)(ibase + (2 * py0 + r) * 80);
  const size_t ob = (size_t)(n0 + img_w) * 1176;
  const bool store_lane = (l16 & 3) == 0;
  for (int it = 0; it < 7; ++it) {
    const int py = py0 + it;
    floatx4 acc0, acc1;
#pragma unroll
    for (int r = 0; r < 4; r++) { acc0[r] = 0.f; acc1[r] = 0.f; }
#pragma unroll
    for (int kc = 0; kc < 6; kc++) {
      acc0 = __builtin_amdgcn_mfma_f32_16x16x32_f16(a[kc], bfr[0][kc], acc0, 0, 0, 0);
      acc1 = __builtin_amdgcn_mfma_f32_16x16x32_f16(a[kc], bfr[1][kc], acc1, 0, 0, 0);
    }
    if (it < 6) {
      a[0] = a[2]; a[1] = a[3]; a[2] = a[4]; a[3] = a[5];
      a[4] = *(const half8_a8*)(ibase + (2 * py + 6) * 80);
      a[5] = *(const half8_a8*)(ibase + (2 * py + 7) * 80);
    }
    float p0[4], p1[4];
#pragma unroll
    for (int r = 0; r < 4; r++) {
      p0[r] = fmaxf(pool4_dpp(acc0[r]) + bias0, 0.f);
      p1[r] = fmaxf(pool4_dpp(acc1[r]) + bias1, 0.f);
    }
    if (store_lane) {
      union { _Float16 h[2]; unsigned u; } s01, s23;
      s01.h[0] = (_Float16)p0[0]; s01.h[1] = (_Float16)p0[1];
      s23.h[0] = (_Float16)p0[2]; s23.h[1] = (_Float16)p0[3];
      _Float16* dst = h1 + ob + co_n * 196 + py * 14 + q * 4;
      *(unsigned*)dst = s01.u;
      if (q < 3) *(unsigned*)(dst + 2) = s23.u;
      if (co1 < 6) {
        union { _Float16 h[2]; unsigned u; } t01, t23;
        t01.h[0] = (_Float16)p1[0]; t01.h[1] = (_Float16)p1[1];
        t23.h[0] = (_Float16)p1[2]; t23.h[1] = (_Float16)p1[3];
        _Float16* dst1 = h1 + ob + co1 * 196 + py * 14 + q * 4;
        *(unsigned*)dst1 = t01.u;
        if (q < 3) *(unsigned*)(dst1 + 2) = t23.u;
      }
    }
  }
}

// ---------------- conv2 via MFMA, corner-in-M, 4 shift copies (unchanged)
__global__ __launch_bounds__(256) void k_conv2(const _Float16* __restrict__ h1,
    const _Float16* __restrict__ B2M, const float* __restrict__ b2,
    _Float16* __restrict__ h2) {
  __shared__ __align__(16) char sm[22272];
  const int t = threadIdx.x;
  const int n0 = blockIdx.x * 2;
  if (t < 168) {
    const int img = t / 84, rem = t - img * 84;
    const int ci = rem / 14, y = rem - ci * 14;
    const unsigned* src =
        (const unsigned*)(h1 + (size_t)(n0 + img) * 1176 + ci * 196 + y * 14);
    unsigned u[10];
#pragma unroll
    for (int k = 0; k < 7; k++) u[k] = src[k];
    u[7] = 0u; u[8] = 0u; u[9] = 0u;
    char* base = sm + img * 11136 + ci * 1856 + y * 32;
#pragma unroll
    for (int ww = 0; ww < 8; ww++) {
      *(unsigned*)(base + 4 * ww) = u[ww];
      *(unsigned*)(base + 464 + 4 * ww) = (u[ww] >> 16) | (u[ww + 1] << 16);
      *(unsigned*)(base + 928 + 4 * ww) = u[ww + 1];
      *(unsigned*)(base + 1392 + 4 * ww) = (u[ww + 1] >> 16) | (u[ww + 2] << 16);
    }
  }
  if (t < 32) {
    const int im = t >> 4;
    h2[(size_t)(n0 + im) * 416 + 400 + (t & 15)] = (_Float16)0.f;
  }
  __syncthreads();
  const int w = t >> 6, lane = t & 63;
  const int l16 = lane & 15, q = lane >> 4;
  int C2[8];
#pragma unroll
  for (int kc = 0; kc < 8; kc++) {
    const int pidx = kc * 4 + q;
    C2[kc] = (pidx < 30) ? (pidx / 5) * 1856 + (pidx % 5) * 32 : 0;
  }
  half8 bfr[8];
#pragma unroll
  for (int kc = 0; kc < 8; kc++)
    bfr[kc] = *(const half8*)(B2M + (size_t)l16 * 256 + kc * 32 + q * 8);
  const float bias = b2[l16];
  for (int mt = w; mt < 13; mt += 4) {
    const int m = min(mt * 16 + l16, 199);
    const int pos = m >> 2, cy = (m >> 1) & 1, cx = m & 1;
    const int img = pos / 25, p = pos - img * 25;
    const int py = p / 5, px = p - py * 5;
    const int h = 2 * px + cx, s = h & 3;
    const char* base =
        sm + img * 11136 + s * 464 + (2 * py + cy) * 32 + (h - s) * 2;
    half8 a[8];
#pragma unroll
    for (int kc = 0; kc < 8; kc++) a[kc] = *(const half8_a8*)(base + C2[kc]);
    floatx4 acc;
#pragma unroll
    for (int r = 0; r < 4; r++) acc[r] = 0.f;
#pragma unroll
    for (int kc = 0; kc < 8; kc++)
      acc = __builtin_amdgcn_mfma_f32_16x16x32_f16(a[kc], bfr[kc], acc, 0, 0, 0);
    const float v = fmaxf(fmaxf(acc[0], acc[1]), fmaxf(acc[2], acc[3]));
    const int posL = mt * 4 + q;
    if (posL < 50) {
      const int im = posL / 25, pp = posL - im * 25;
      h2[(size_t)(n0 + im) * 416 + l16 * 25 + pp] =
          (_Float16)fmaxf(v + bias, 0.f);
    }
  }
}

// ---------------- fused MLP via f16 MFMA (unchanged)
__global__ __launch_bounds__(256) void k_mlp(
    const _Float16* __restrict__ h2, const _Float16* __restrict__ w1,
    const float* __restrict__ bf1, const _Float16* __restrict__ w2,
    const float* __restrict__ bf2, const _Float16* __restrict__ wg,
    const float* __restrict__ al, const float* __restrict__ ar,
    float* __restrict__ z, float* __restrict__ el, float* __restrict__ er) {
  __shared__ __align__(16) _Float16 h3s[32 * 136];
  __shared__ __align__(16) _Float16 h4s[32 * 104];
  __shared__ float zs[32 * 17];
  const int t = threadIdx.x;
  const int w = t >> 6, lane = t & 63;
  const int l16 = lane & 15, q = lane >> 4;
  const int row0 = blockIdx.x * 32;
  for (int i = t; i < 2176; i += 256) ((float*)h3s)[i] = 0.f;
  for (int i = t; i < 1664; i += 256) ((float*)h4s)[i] = 0.f;
  const int rt = w & 1, cg = w >> 1;
  const int am = row0 + rt * 16 + l16;
  floatx4 acc[4];
#pragma unroll
  for (int ct = 0; ct < 4; ct++)
#pragma unroll
    for (int r = 0; r < 4; r++) acc[ct][r] = 0.f;
  const half8* Ag = (const half8*)(h2 + (size_t)am * 416 + q * 8);
  for (int kc = 0; kc < 13; kc++) {
    half8 a = Ag[kc * 4];
#pragma unroll
    for (int ct = 0; ct < 4; ct++) {
      const int n = cg * 64 + ct * 16 + l16;
      half8 b = *(const half8*)(w1 + (size_t)n * 416 + kc * 32 + q * 8);
      acc[ct] = __builtin_amdgcn_mfma_f32_16x16x32_f16(a, b, acc[ct], 0, 0, 0);
    }
  }
  __syncthreads();
#pragma unroll
  for (int ct = 0; ct < 4; ct++) {
    const int n = cg * 64 + ct * 16 + l16;
    if (n < 120) {
      const float bias = bf1[n];
#pragma unroll
      for (int r = 0; r < 4; r++) {
        const int rr = rt * 16 + q * 4 + r;
        h3s[rr * 136 + n] = (_Float16)fmaxf(acc[ct][r] + bias, 0.f);
      }
    }
  }
  __syncthreads();
  const int cbase2 = (w >> 1) * 3;
  floatx4 acc2[3];
#pragma unroll
  for (int ct = 0; ct < 3; ct++)
#pragma unroll
    for (int r = 0; r < 4; r++) acc2[ct][r] = 0.f;
  const _Float16* A2 = h3s + (rt * 16 + l16) * 136 + q * 8;
  for (int kc = 0; kc < 4; kc++) {
    half8 a = *(const half8*)(A2 + kc * 32);
#pragma unroll
    for (int ct = 0; ct < 3; ct++) {
      const int n = (cbase2 + ct) * 16 + l16;
      half8 b = *(const half8*)(w2 + (size_t)n * 128 + kc * 32 + q * 8);
      acc2[ct] = __builtin_amdgcn_mfma_f32_16x16x32_f16(a, b, acc2[ct], 0, 0, 0);
    }
  }
  __syncthreads();
#pragma unroll
  for (int ct = 0; ct < 3; ct++) {
    const int n = (cbase2 + ct) * 16 + l16;
    if (n < 84) {
      const float bias = bf2[n];
#pragma unroll
      for (int r = 0; r < 4; r++) {
        const int rr = rt * 16 + q * 4 + r;
        h4s[rr * 104 + n] = (_Float16)fmaxf(acc2[ct][r] + bias, 0.f);
      }
    }
  }
  __syncthreads();
  if (w < 2) {
    floatx4 acc3;
#pragma unroll
    for (int r = 0; r < 4; r++) acc3[r] = 0.f;
    const _Float16* A3 = h4s + (w * 16 + l16) * 104 + q * 8;
    for (int kc = 0; kc < 3; kc++) {
      half8 a = *(const half8*)(A3 + kc * 32);
      half8 b = *(const half8*)(wg + (size_t)l16 * 96 + kc * 32 + q * 8);
      acc3 = __builtin_amdgcn_mfma_f32_16x16x32_f16(a, b, acc3, 0, 0, 0);
    }
#pragma unroll
    for (int r = 0; r < 4; r++) {
      const int rr = w * 16 + q * 4 + r;
      zs[rr * 17 + l16] = acc3[r];
      if (l16 < 10) z[(size_t)(row0 + rr) * 10 + l16] = acc3[r];
    }
  }
  __syncthreads();
  if (t < 32) {
    float e1 = 0.f, e2 = 0.f;
#pragma unroll
    for (int d = 0; d < 10; d++) {
      const float zv = zs[t * 17 + d];
      e1 += zv * al[d];
      e2 += zv * ar[d];
    }
    el[row0 + t] = e1;
    er[row0 + t] = e2;
  }
}

// ---------------- max over el
__global__ __launch_bounds__(256) void k_elmax(const float* __restrict__ el,
                                               float* __restrict__ out) {
  __shared__ float red[4];
  const int t = threadIdx.x;
  float m = -1e30f;
  for (int i = t; i < 8192; i += 256) m = fmaxf(m, el[i]);
#pragma unroll
  for (int off = 32; off > 0; off >>= 1) m = fmaxf(m, __shfl_down(m, off, 64));
  if ((t & 63) == 0) red[t >> 6] = m;
  __syncthreads();
  if (t == 0) out[0] = fmaxf(fmaxf(red[0], red[1]), fmaxf(red[2], red[3]));
}

// ---------------- attention partials: 4 dst i per thread (LDS reads amortized)
__global__ __launch_bounds__(256) void k_attn(const float* __restrict__ z,
    const float* __restrict__ el, const float* __restrict__ er,
    const float* __restrict__ elmax, float* __restrict__ part) {
  __shared__ __align__(16) float zsm[256 * 12];
  const int t = threadIdx.x;
  const int split = blockIdx.y;
  const int jbase = split * 256;
  for (int idx = t; idx < 2560; idx += 256) {
    int jj = idx / 10, d = idx - jj * 10;
    zsm[jj * 12 + d] = z[(size_t)jbase * 10 + idx];
  }
  zsm[t * 12 + 10] = el[jbase + t];
  const int i0 = blockIdx.x * 1024 + t;
  const float mx = elmax[0];
  float eri[4], mi[4];
#pragma unroll
  for (int g = 0; g < 4; g++) {
    eri[g] = er[i0 + g * 256];
    const float s0 = eri[g] + mx;
    mi[g] = fmaxf(s0, 0.2f * s0);
  }
  float num[4][10];
#pragma unroll
  for (int g = 0; g < 4; g++)
#pragma unroll
    for (int d = 0; d < 10; d++) num[g][d] = 0.f;
  float den[4] = {0.f, 0.f, 0.f, 0.f};
  __syncthreads();
#pragma unroll 2
  for (int jj = 0; jj < 256; jj++) {
    const float4 za = *(const float4*)(zsm + jj * 12);
    const float4 zb = *(const float4*)(zsm + jj * 12 + 4);
    const float4 zc = *(const float4*)(zsm + jj * 12 + 8);  // z8,z9,el,pad
    const float elj = zc.z;
#pragma unroll
    for (int g = 0; g < 4; g++) {
      const float s2 = eri[g] + elj;
      const float lr = fmaxf(s2, 0.2f * s2);
      const float wgt = __expf(lr - mi[g]);
      den[g] += wgt;
      num[g][0] += wgt * za.x; num[g][1] += wgt * za.y;
      num[g][2] += wgt * za.z; num[g][3] += wgt * za.w;
      num[g][4] += wgt * zb.x; num[g][5] += wgt * zb.y;
      num[g][6] += wgt * zb.z; num[g][7] += wgt * zb.w;
      num[g][8] += wgt * zc.x; num[g][9] += wgt * zc.y;
    }
  }
#pragma unroll
  for (int g = 0; g < 4; g++) {
    float* pp = part + (size_t)split * 98304 + i0 + g * 256;
#pragma unroll
    for (int d = 0; d < 10; d++) pp[d * 8192] = num[g][d];
    pp[10 * 8192] = den[g];
  }
}

// ---------------- combine partials: 256 blocks, 2-stage LDS reduction
__global__ __launch_bounds__(256) void k_final(const float* __restrict__ part,
    const float* __restrict__ bg, float* __restrict__ out) {
  __shared__ float red[8][32][12];
  const int t = threadIdx.x;
  const int i0 = blockIdx.x * 32;
  const int il = t & 31, sg = t >> 5;
  float v[11];
#pragma unroll
  for (int d = 0; d < 11; d++) v[d] = 0.f;
  for (int u = 0; u < 4; u++) {
    const float* pp = part + (size_t)(sg * 4 + u) * 98304 + i0 + il;
#pragma unroll
    for (int d = 0; d < 11; d++) v[d] += pp[d * 8192];
  }
#pragma unroll
  for (int d = 0; d < 11; d++) red[sg][il][d] = v[d];
  __syncthreads();
  for (int t2 = t; t2 < 352; t2 += 256) {
    const int ii = t2 / 11, d = t2 - ii * 11;
    if (d < 10) {
      float num = 0.f, den = 0.f;
#pragma unroll
      for (int s = 0; s < 8; s++) {
        num += red[s][ii][d];
        den += red[s][ii][10];
      }
      out[(size_t)(i0 + ii) * 10 + d] = num / den + bg[d];
    }
  }
}

extern "C" void kernel_launch(void* const* d_in, const int* in_sizes, int n_in,
                              void* d_out, int out_size, void* d_ws, size_t ws_size,
                              hipStream_t stream) {
  const float* x   = (const float*)d_in[0];
  const float* W1  = (const float*)d_in[1];
  const float* b1  = (const float*)d_in[2];
  const float* W2  = (const float*)d_in[3];
  const float* b2  = (const float*)d_in[4];
  const float* Wf1 = (const float*)d_in[5];
  const float* bf1 = (const float*)d_in[6];
  const float* Wf2 = (const float*)d_in[7];
  const float* bf2 = (const float*)d_in[8];
  const float* Wg  = (const float*)d_in[9];
  const float* al  = (const float*)d_in[10];
  const float* ar  = (const float*)d_in[11];
  const float* bg  = (const float*)d_in[12];
  float* out = (float*)d_out;

  float* ws = (float*)d_ws;
  _Float16* h1f = (_Float16*)ws;                        // 8192*1176 f16
  float* p = ws + (size_t)8192 * 588;
  _Float16* h2f = (_Float16*)p;                         // 8192*416 f16
  p += (size_t)8192 * 208;
  float* z   = p; p += (size_t)8192 * 10;
  float* el  = p; p += 8192;
  float* er  = p; p += 8192;
  float* emx = p; p += 16;
  _Float16* w1f = (_Float16*)p; p += 26624;             // 128*416 f16
  _Float16* w2f = (_Float16*)p; p += 6144;              // 96*128 f16
  _Float16* wgf = (_Float16*)p; p += 768;               // 16*96 f16
  _Float16* B1g = (_Float16*)p; p += 3072;              // 32*192 f16
  _Float16* B2g = (_Float16*)p; p += 2048;              // 16*256 f16
  float* part = ws;                                     // aliases h1 (dead after conv2)

  k_prep<<<302, 256, 0, stream>>>(Wf1, Wf2, Wg, W1, W2, w1f, w2f, wgf, B1g, B2g);
  k_conv1<<<4096, 256, 0, stream>>>(x, B1g, b1, h1f);
  k_conv2<<<4096, 256, 0, stream>>>(h1f, B2g, b2, h2f);
  k_mlp<<<256, 256, 0, stream>>>(h2f, w1f, bf1, w2f, bf2, wgf, al, ar, z, el, er);
  k_elmax<<<1, 256, 0, stream>>>(el, emx);
  dim3 ag(8, 32);
  k_attn<<<ag, 256, 0, stream>>>(z, el, er, emx, part);
  k_final<<<256, 256, 0, stream>>>(part, bg, out);
}

// Round 7
// 284.427 us; speedup vs baseline: 1.6118x; 1.0076x over previous
//
#include <hip/hip_runtime.h>
#include <hip/hip_bf16.h>

typedef _Float16 half8 __attribute__((ext_vector_type(8)));
typedef __attribute__((aligned(8))) half8 half8_a8;  // -> 2x ds_read_b64
typedef float floatx4 __attribute__((ext_vector_type(4)));

#define LOG2E 1.44269504088896340736f

// DPP cross-lane max within quads (pooling over corner = lane&3), no DS pipe
__device__ __forceinline__ float pool4_dpp(float v) {
  int s1 = __builtin_amdgcn_update_dpp(0, __float_as_int(v), 0xB1, 0xF, 0xF, true); // xor1
  float v1 = fmaxf(v, __int_as_float(s1));
  int s2 = __builtin_amdgcn_update_dpp(0, __float_as_int(v1), 0x4E, 0xF, 0xF, true); // xor2
  return fmaxf(v1, __int_as_float(s2));
}

// ---------------- prep: f16 MLP weights + conv B-matrices
__global__ __launch_bounds__(256) void k_prep(const float* __restrict__ Wf1,
    const float* __restrict__ Wf2, const float* __restrict__ Wg,
    const float* __restrict__ W1, const float* __restrict__ W2,
    _Float16* __restrict__ w1f, _Float16* __restrict__ w2f,
    _Float16* __restrict__ wgf, _Float16* __restrict__ B1,
    _Float16* __restrict__ B2M) {
  const int i = blockIdx.x * 256 + threadIdx.x;
  if (i < 53248) {
    const int n = i / 416, k = i - n * 416;
    w1f[i] = (_Float16)((n < 120 && k < 400) ? Wf1[n * 400 + k] : 0.f);
  } else if (i < 65536) {
    const int j = i - 53248;
    const int n = j >> 7, k = j & 127;
    w2f[j] = (_Float16)((n < 84 && k < 120) ? Wf2[n * 120 + k] : 0.f);
  } else if (i < 67072) {
    const int g = i - 65536;
    const int n = g / 96, k = g - n * 96;
    wgf[g] = (_Float16)((n < 10 && k < 84) ? Wg[n * 84 + k] : 0.f);
  } else if (i < 73216) {
    const int g = i - 67072;
    const int n = g / 192, k = g - n * 192;
    const int co = n >> 2, cy = (n >> 1) & 1, cx = n & 1;
    const int pidx = k >> 3, j = k & 7;
    const int r = pidx >> 2, ci = pidx & 3;
    float v = 0.f;
    if (co < 6 && ci < 3) {
      const int ky = r - cy, kx = j - cx;
      if (ky >= 0 && ky < 5 && kx >= 0 && kx < 5)
        v = W1[((co * 3 + ci) * 5 + ky) * 5 + kx];
    }
    B1[g] = (_Float16)v;
  } else if (i < 77312) {
    const int g = i - 73216;
    const int n = g >> 8, k = g & 255;
    float v = 0.f;
    if (k < 240) {
      const int ci = k / 40, rem = k - ci * 40, r = rem >> 3, j = rem & 7;
      if (j < 5) v = W2[((n * 6 + ci) * 5 + r) * 5 + j];
    }
    B2M[g] = (_Float16)v;
  }
}

// ---------------- conv1 via MFMA: 1 img/block (LDS 15.5KB -> ~8 blocks/CU)
// Per (py) m-tile: m=px (l16), n=co*4+corner (24 of 32), K=192 (kc=r, q=ci).
// Rolling 6-row register window over py; DPP quad pooling; one barrier.
__global__ __launch_bounds__(256) void k_conv1(const float* __restrict__ x,
    const _Float16* __restrict__ B1, const float* __restrict__ b1,
    _Float16* __restrict__ h1) {
  __shared__ __align__(16) char sm[15552];
  const int t = threadIdx.x;
  const float4* x4 = (const float4*)(x + (size_t)blockIdx.x * 3072);
  for (int i = t; i < 768; i += 256) {
    const float4 v = x4[i];
    const int ci = i >> 8, rem2 = i & 255;
    const int y = rem2 >> 3, c = rem2 & 7;
    union { _Float16 h[2]; unsigned u; } p01, p23;
    p01.h[0] = (_Float16)v.x; p01.h[1] = (_Float16)v.y;
    p23.h[0] = (_Float16)v.z; p23.h[1] = (_Float16)v.w;
    char* row = sm + ci * 5184 + y * 80;
    *(uint2*)(row + 8 * c) = make_uint2(p01.u, p23.u);
    *(unsigned*)(row + 2596 + 8 * c) = p01.u;
    *(unsigned*)(row + 2600 + 8 * c) = p23.u;
  }
  if (t < 96) {
    const int ci = t >> 5, y = t & 31;
    *(unsigned*)(sm + ci * 5184 + 2596 + y * 80 + 64) = 0u;
  }
  __syncthreads();
  const int w4 = t >> 6, lane = t & 63;
  const int l16 = lane & 15, q = lane >> 4;
  const int px = l16;
  const int colOff = (px & 1) ? (2596 + 4 * px) : (4 * px);
  const char* base = sm + ((q == 3) ? 0 : q * 5184) + colOff;
  half8 bfr[2][6];
#pragma unroll
  for (int nt = 0; nt < 2; nt++)
#pragma unroll
    for (int kc = 0; kc < 6; kc++)
      bfr[nt][kc] =
          *(const half8*)(B1 + (size_t)(nt * 16 + l16) * 192 + kc * 32 + q * 8);
  const int co_n = l16 >> 2;
  const int co1 = 4 + co_n;
  const float bias0 = b1[co_n];
  const float bias1 = (co1 < 6) ? b1[co1] : 0.f;
  const int py0 = (7 * w4) >> 1;
  const int py1 = (7 * (w4 + 1)) >> 1;   // waves cover py {0-2,3-6,7-9,10-13}
  half8 a[6];
#pragma unroll
  for (int r = 0; r < 6; r++)
    a[r] = *(const half8_a8*)(base + (2 * py0 + r) * 80);
  const size_t ob = (size_t)blockIdx.x * 1176;
  const bool store_lane = (l16 & 3) == 0;
  for (int py = py0; py < py1; ++py) {
    floatx4 acc0, acc1;
#pragma unroll
    for (int r = 0; r < 4; r++) { acc0[r] = 0.f; acc1[r] = 0.f; }
#pragma unroll
    for (int kc = 0; kc < 6; kc++) {
      acc0 = __builtin_amdgcn_mfma_f32_16x16x32_f16(a[kc], bfr[0][kc], acc0, 0, 0, 0);
      acc1 = __builtin_amdgcn_mfma_f32_16x16x32_f16(a[kc], bfr[1][kc], acc1, 0, 0, 0);
    }
    if (py < py1 - 1) {
      a[0] = a[2]; a[1] = a[3]; a[2] = a[4]; a[3] = a[5];
      a[4] = *(const half8_a8*)(base + (2 * py + 6) * 80);
      a[5] = *(const half8_a8*)(base + (2 * py + 7) * 80);
    }
    float p0[4], p1[4];
#pragma unroll
    for (int r = 0; r < 4; r++) {
      p0[r] = fmaxf(pool4_dpp(acc0[r]) + bias0, 0.f);
      p1[r] = fmaxf(pool4_dpp(acc1[r]) + bias1, 0.f);
    }
    if (store_lane) {
      union { _Float16 h[2]; unsigned u; } s01, s23;
      s01.h[0] = (_Float16)p0[0]; s01.h[1] = (_Float16)p0[1];
      s23.h[0] = (_Float16)p0[2]; s23.h[1] = (_Float16)p0[3];
      _Float16* dst = h1 + ob + co_n * 196 + py * 14 + q * 4;
      *(unsigned*)dst = s01.u;
      if (q < 3) *(unsigned*)(dst + 2) = s23.u;
      if (co1 < 6) {
        union { _Float16 h[2]; unsigned u; } t01, t23;
        t01.h[0] = (_Float16)p1[0]; t01.h[1] = (_Float16)p1[1];
        t23.h[0] = (_Float16)p1[2]; t23.h[1] = (_Float16)p1[3];
        _Float16* dst1 = h1 + ob + co1 * 196 + py * 14 + q * 4;
        *(unsigned*)dst1 = t01.u;
        if (q < 3) *(unsigned*)(dst1 + 2) = t23.u;
      }
    }
  }
}

// ---------------- conv2 via MFMA, corner-in-M, 4 shift copies (unchanged)
__global__ __launch_bounds__(256) void k_conv2(const _Float16* __restrict__ h1,
    const _Float16* __restrict__ B2M, const float* __restrict__ b2,
    _Float16* __restrict__ h2) {
  __shared__ __align__(16) char sm[22272];
  const int t = threadIdx.x;
  const int n0 = blockIdx.x * 2;
  if (t < 168) {
    const int img = t / 84, rem = t - img * 84;
    const int ci = rem / 14, y = rem - ci * 14;
    const unsigned* src =
        (const unsigned*)(h1 + (size_t)(n0 + img) * 1176 + ci * 196 + y * 14);
    unsigned u[10];
#pragma unroll
    for (int k = 0; k < 7; k++) u[k] = src[k];
    u[7] = 0u; u[8] = 0u; u[9] = 0u;
    char* base = sm + img * 11136 + ci * 1856 + y * 32;
#pragma unroll
    for (int ww = 0; ww < 8; ww++) {
      *(unsigned*)(base + 4 * ww) = u[ww];
      *(unsigned*)(base + 464 + 4 * ww) = (u[ww] >> 16) | (u[ww + 1] << 16);
      *(unsigned*)(base + 928 + 4 * ww) = u[ww + 1];
      *(unsigned*)(base + 1392 + 4 * ww) = (u[ww + 1] >> 16) | (u[ww + 2] << 16);
    }
  }
  if (t < 32) {
    const int im = t >> 4;
    h2[(size_t)(n0 + im) * 416 + 400 + (t & 15)] = (_Float16)0.f;
  }
  __syncthreads();
  const int w = t >> 6, lane = t & 63;
  const int l16 = lane & 15, q = lane >> 4;
  int C2[8];
#pragma unroll
  for (int kc = 0; kc < 8; kc++) {
    const int pidx = kc * 4 + q;
    C2[kc] = (pidx < 30) ? (pidx / 5) * 1856 + (pidx % 5) * 32 : 0;
  }
  half8 bfr[8];
#pragma unroll
  for (int kc = 0; kc < 8; kc++)
    bfr[kc] = *(const half8*)(B2M + (size_t)l16 * 256 + kc * 32 + q * 8);
  const float bias = b2[l16];
  for (int mt = w; mt < 13; mt += 4) {
    const int m = min(mt * 16 + l16, 199);
    const int pos = m >> 2, cy = (m >> 1) & 1, cx = m & 1;
    const int img = pos / 25, p = pos - img * 25;
    const int py = p / 5, px = p - py * 5;
    const int h = 2 * px + cx, s = h & 3;
    const char* base =
        sm + img * 11136 + s * 464 + (2 * py + cy) * 32 + (h - s) * 2;
    half8 a[8];
#pragma unroll
    for (int kc = 0; kc < 8; kc++) a[kc] = *(const half8_a8*)(base + C2[kc]);
    floatx4 acc;
#pragma unroll
    for (int r = 0; r < 4; r++) acc[r] = 0.f;
#pragma unroll
    for (int kc = 0; kc < 8; kc++)
      acc = __builtin_amdgcn_mfma_f32_16x16x32_f16(a[kc], bfr[kc], acc, 0, 0, 0);
    const float v = fmaxf(fmaxf(acc[0], acc[1]), fmaxf(acc[2], acc[3]));
    const int posL = mt * 4 + q;
    if (posL < 50) {
      const int im = posL / 25, pp = posL - im * 25;
      h2[(size_t)(n0 + im) * 416 + l16 * 25 + pp] =
          (_Float16)fmaxf(v + bias, 0.f);
    }
  }
}

// ---------------- fused MLP via f16 MFMA; emits zT f16 [16][8192] (row10=ones)
// and el/er pre-scaled by log2(e) for exp2-domain attention.
__global__ __launch_bounds__(256) void k_mlp(
    const _Float16* __restrict__ h2, const _Float16* __restrict__ w1,
    const float* __restrict__ bf1, const _Float16* __restrict__ w2,
    const float* __restrict__ bf2, const _Float16* __restrict__ wg,
    const float* __restrict__ al, const float* __restrict__ ar,
    _Float16* __restrict__ zT, float* __restrict__ el, float* __restrict__ er) {
  __shared__ __align__(16) _Float16 h3s[32 * 136];
  __shared__ __align__(16) _Float16 h4s[32 * 104];
  __shared__ float zs[32 * 17];
  const int t = threadIdx.x;
  const int w = t >> 6, lane = t & 63;
  const int l16 = lane & 15, q = lane >> 4;
  const int row0 = blockIdx.x * 32;
  for (int i = t; i < 2176; i += 256) ((float*)h3s)[i] = 0.f;
  for (int i = t; i < 1664; i += 256) ((float*)h4s)[i] = 0.f;
  const int rt = w & 1, cg = w >> 1;
  const int am = row0 + rt * 16 + l16;
  floatx4 acc[4];
#pragma unroll
  for (int ct = 0; ct < 4; ct++)
#pragma unroll
    for (int r = 0; r < 4; r++) acc[ct][r] = 0.f;
  const half8* Ag = (const half8*)(h2 + (size_t)am * 416 + q * 8);
  for (int kc = 0; kc < 13; kc++) {
    half8 a = Ag[kc * 4];
#pragma unroll
    for (int ct = 0; ct < 4; ct++) {
      const int n = cg * 64 + ct * 16 + l16;
      half8 b = *(const half8*)(w1 + (size_t)n * 416 + kc * 32 + q * 8);
      acc[ct] = __builtin_amdgcn_mfma_f32_16x16x32_f16(a, b, acc[ct], 0, 0, 0);
    }
  }
  __syncthreads();
#pragma unroll
  for (int ct = 0; ct < 4; ct++) {
    const int n = cg * 64 + ct * 16 + l16;
    if (n < 120) {
      const float bias = bf1[n];
#pragma unroll
      for (int r = 0; r < 4; r++) {
        const int rr = rt * 16 + q * 4 + r;
        h3s[rr * 136 + n] = (_Float16)fmaxf(acc[ct][r] + bias, 0.f);
      }
    }
  }
  __syncthreads();
  const int cbase2 = (w >> 1) * 3;
  floatx4 acc2[3];
#pragma unroll
  for (int ct = 0; ct < 3; ct++)
#pragma unroll
    for (int r = 0; r < 4; r++) acc2[ct][r] = 0.f;
  const _Float16* A2 = h3s + (rt * 16 + l16) * 136 + q * 8;
  for (int kc = 0; kc < 4; kc++) {
    half8 a = *(const half8*)(A2 + kc * 32);
#pragma unroll
    for (int ct = 0; ct < 3; ct++) {
      const int n = (cbase2 + ct) * 16 + l16;
      half8 b = *(const half8*)(w2 + (size_t)n * 128 + kc * 32 + q * 8);
      acc2[ct] = __builtin_amdgcn_mfma_f32_16x16x32_f16(a, b, acc2[ct], 0, 0, 0);
    }
  }
  __syncthreads();
#pragma unroll
  for (int ct = 0; ct < 3; ct++) {
    const int n = (cbase2 + ct) * 16 + l16;
    if (n < 84) {
      const float bias = bf2[n];
#pragma unroll
      for (int r = 0; r < 4; r++) {
        const int rr = rt * 16 + q * 4 + r;
        h4s[rr * 104 + n] = (_Float16)fmaxf(acc2[ct][r] + bias, 0.f);
      }
    }
  }
  __syncthreads();
  if (w < 2) {
    floatx4 acc3;
#pragma unroll
    for (int r = 0; r < 4; r++) acc3[r] = 0.f;
    const _Float16* A3 = h4s + (w * 16 + l16) * 104 + q * 8;
    for (int kc = 0; kc < 3; kc++) {
      half8 a = *(const half8*)(A3 + kc * 32);
      half8 b = *(const half8*)(wg + (size_t)l16 * 96 + kc * 32 + q * 8);
      acc3 = __builtin_amdgcn_mfma_f32_16x16x32_f16(a, b, acc3, 0, 0, 0);
    }
#pragma unroll
    for (int r = 0; r < 4; r++) {
      const int rr = w * 16 + q * 4 + r;
      zs[rr * 17 + l16] = acc3[r];
    }
  }
  __syncthreads();
  if (t < 32) {
    float e1 = 0.f, e2 = 0.f;
#pragma unroll
    for (int d = 0; d < 10; d++) {
      const float zv = zs[t * 17 + d];
      e1 += zv * al[d];
      e2 += zv * ar[d];
    }
    el[row0 + t] = e1 * LOG2E;
    er[row0 + t] = e2 * LOG2E;
  }
  // zT[d][i] f16; row 10 = ones (denominator column)
  for (int idx = t; idx < 352; idx += 256) {
    const int d = idx >> 5, c = idx & 31;
    zT[(size_t)d * 8192 + row0 + c] =
        (d < 10) ? (_Float16)zs[c * 17 + d] : (_Float16)1.0f;
  }
}

// ---------------- max over el (scaled domain; max commutes w/ pos scale)
__global__ __launch_bounds__(256) void k_elmax(const float* __restrict__ el,
                                               float* __restrict__ out) {
  __shared__ float red[4];
  const int t = threadIdx.x;
  float m = -1e30f;
  for (int i = t; i < 8192; i += 256) m = fmaxf(m, el[i]);
#pragma unroll
  for (int off = 32; off > 0; off >>= 1) m = fmaxf(m, __shfl_down(m, off, 64));
  if ((t & 63) == 0) red[t >> 6] = m;
  __syncthreads();
  if (t == 0) out[0] = fmaxf(fmaxf(red[0], red[1]), fmaxf(red[2], red[3]));
}

// ---------------- attention via MFMA: A = on-the-fly exp2 weights (f16),
// B = zT fragments. Wave = 16 dst rows; block = 64 rows; 8 j-splits of 1024.
// No LDS, no barriers. D[row=i, col=d] with col 10 = denominator.
__global__ __launch_bounds__(256) void k_attn(const _Float16* __restrict__ zT,
    const float* __restrict__ el, const float* __restrict__ er,
    const float* __restrict__ elmax, float* __restrict__ part) {
  const int t = threadIdx.x;
  const int w = t >> 6, lane = t & 63;
  const int l16 = lane & 15, q = lane >> 4;
  const int itile = blockIdx.x * 64 + w * 16;
  const int jb = blockIdx.y * 1024;
  const float mx = elmax[0];
  const float eri = er[itile + l16];
  const float s0 = eri + mx;
  const float mi = fmaxf(s0, 0.2f * s0);
  floatx4 acc;
#pragma unroll
  for (int r = 0; r < 4; r++) acc[r] = 0.f;
  const float* elp = el + jb + q * 8;
  const _Float16* ztp = zT + (size_t)l16 * 8192 + jb + q * 8;
  for (int jc = 0; jc < 32; jc++) {
    const float4 e0 = *(const float4*)(elp + jc * 32);
    const float4 e1 = *(const float4*)(elp + jc * 32 + 4);
    float wf[8];
    const float ej[8] = {e0.x, e0.y, e0.z, e0.w, e1.x, e1.y, e1.z, e1.w};
#pragma unroll
    for (int u = 0; u < 8; u++) {
      const float s = eri + ej[u];
      const float lr = fmaxf(s, 0.2f * s);
      wf[u] = exp2f(lr - mi);
    }
    half8 a;
#pragma unroll
    for (int u = 0; u < 8; u++) a[u] = (_Float16)wf[u];
    const half8 b = *(const half8*)(ztp + jc * 32);
    acc = __builtin_amdgcn_mfma_f32_16x16x32_f16(a, b, acc, 0, 0, 0);
  }
  if (l16 < 11) {
    float* pp = part + (size_t)blockIdx.y * 98304 + (size_t)l16 * 8192 + itile + q * 4;
#pragma unroll
    for (int r = 0; r < 4; r++) pp[r] = acc[r];
  }
}

// ---------------- combine 8 partial splits, divide, add bias
__global__ __launch_bounds__(256) void k_final(const float* __restrict__ part,
    const float* __restrict__ bg, float* __restrict__ out) {
  __shared__ float red[8][32][12];
  const int t = threadIdx.x;
  const int i0 = blockIdx.x * 32;
  const int il = t & 31, sg = t >> 5;
  const float* pp = part + (size_t)sg * 98304 + i0 + il;
#pragma unroll
  for (int d = 0; d < 11; d++) red[sg][il][d] = pp[d * 8192];
  __syncthreads();
  for (int t2 = t; t2 < 352; t2 += 256) {
    const int ii = t2 / 11, d = t2 - ii * 11;
    if (d < 10) {
      float num = 0.f, den = 0.f;
#pragma unroll
      for (int s = 0; s < 8; s++) {
        num += red[s][ii][d];
        den += red[s][ii][10];
      }
      out[(size_t)(i0 + ii) * 10 + d] = num / den + bg[d];
    }
  }
}

extern "C" void kernel_launch(void* const* d_in, const int* in_sizes, int n_in,
                              void* d_out, int out_size, void* d_ws, size_t ws_size,
                              hipStream_t stream) {
  const float* x   = (const float*)d_in[0];
  const float* W1  = (const float*)d_in[1];
  const float* b1  = (const float*)d_in[2];
  const float* W2  = (const float*)d_in[3];
  const float* b2  = (const float*)d_in[4];
  const float* Wf1 = (const float*)d_in[5];
  const float* bf1 = (const float*)d_in[6];
  const float* Wf2 = (const float*)d_in[7];
  const float* bf2 = (const float*)d_in[8];
  const float* Wg  = (const float*)d_in[9];
  const float* al  = (const float*)d_in[10];
  const float* ar  = (const float*)d_in[11];
  const float* bg  = (const float*)d_in[12];
  float* out = (float*)d_out;

  float* ws = (float*)d_ws;
  _Float16* h1f = (_Float16*)ws;                        // 8192*1176 f16
  float* p = ws + (size_t)8192 * 588;
  _Float16* h2f = (_Float16*)p;                         // 8192*416 f16
  p += (size_t)8192 * 208;
  _Float16* zTf = (_Float16*)p; p += 65536;             // 16*8192 f16
  float* el  = p; p += 8192;
  float* er  = p; p += 8192;
  float* emx = p; p += 16;
  _Float16* w1f = (_Float16*)p; p += 26624;             // 128*416 f16
  _Float16* w2f = (_Float16*)p; p += 6144;              // 96*128 f16
  _Float16* wgf = (_Float16*)p; p += 768;               // 16*96 f16
  _Float16* B1g = (_Float16*)p; p += 3072;              // 32*192 f16
  _Float16* B2g = (_Float16*)p; p += 2048;              // 16*256 f16
  float* part = ws;                                     // aliases h1 (dead after conv2)

  k_prep<<<302, 256, 0, stream>>>(Wf1, Wf2, Wg, W1, W2, w1f, w2f, wgf, B1g, B2g);
  k_conv1<<<8192, 256, 0, stream>>>(x, B1g, b1, h1f);
  k_conv2<<<4096, 256, 0, stream>>>(h1f, B2g, b2, h2f);
  k_mlp<<<256, 256, 0, stream>>>(h2f, w1f, bf1, w2f, bf2, wgf, al, ar, zTf, el, er);
  k_elmax<<<1, 256, 0, stream>>>(el, emx);
  dim3 ag(128, 8);
  k_attn<<<ag, 256, 0, stream>>>(zTf, el, er, emx, part);
  k_final<<<256, 256, 0, stream>>>(part, bg, out);
}